// Round 8
// baseline (556.821 us; speedup 1.0000x reference)
//
#include <hip/hip_runtime.h>
#include <hip/hip_bf16.h>
#include <math.h>

#define NL 30
#define NM 80
#define Bx 8
#define Tx 8192

typedef short short8 __attribute__((ext_vector_type(8)));
typedef float f32x4 __attribute__((ext_vector_type(4)));
typedef unsigned int u32x2 __attribute__((ext_vector_type(2)));
typedef unsigned int u32x4 __attribute__((ext_vector_type(4)));

__device__ __forceinline__ float bf2f(unsigned short u) {
    union { unsigned int u; float f; } v; v.u = ((unsigned int)u) << 16; return v.f;
}
__device__ __forceinline__ unsigned short f2bf(float f) {
    union { float f; unsigned int u; } v; v.f = f;
    unsigned int r = v.u + 0x7FFFu + ((v.u >> 16) & 1u);
    return (unsigned short)(r >> 16);
}

#if defined(__has_builtin)
#if __has_builtin(__builtin_amdgcn_global_load_lds)
#define HAS_GLL 1
#endif
#endif

__device__ __forceinline__ void gll16(const void* g, void* l) {
#ifdef HAS_GLL
    __builtin_amdgcn_global_load_lds(
        (const __attribute__((address_space(1))) void*)g,
        (__attribute__((address_space(3))) void*)l, 16, 0, 0);
#else
    int lane = threadIdx.x & 63;
    *(u32x4*)((char*)l + lane * 16) = *(const u32x4*)((const char*)g + lane * 16);
#endif
}

// ---------------- merged setup ----------------
// blocks 0-29: wc2 transpose | 30-59: wr2 transpose | 60: skw/oww
// | 61-316: in_conv (256 pos/block)
__global__ __launch_bounds__(512) void setup_kernel(
        const float* __restrict__ dconv_w, const float* __restrict__ rs_w,
        const float* __restrict__ skip_w, const float* __restrict__ out_w,
        unsigned short* __restrict__ wc2, unsigned short* __restrict__ wr2,
        unsigned short* __restrict__ skw16, unsigned short* __restrict__ oww16,
        const float* __restrict__ x, const float* __restrict__ in_w,
        const float* __restrict__ in_b, unsigned short* __restrict__ h0) {
    __shared__ __align__(16) unsigned char smem[49152];
    int blk = blockIdx.x;
    int tid = threadIdx.x;
    if (blk < 30) {
        // ---- wc2: coalesced float4 read (batched) -> LDS swizzle -> coalesced write ----
        int l = blk;
        unsigned short* st = (unsigned short*)smem;   // 24576 bf16 = 48KB
        const f32x4* src4 = (const f32x4*)(dconv_w + (size_t)l * 24576);
        #pragma unroll
        for (int h = 0; h < 2; ++h) {
            f32x4 v[6];
            #pragma unroll
            for (int it = 0; it < 6; ++it)
                v[it] = src4[(h * 6 + it) * 512 + tid];
            #pragma unroll
            for (int it = 0; it < 6; ++it) {
                int chunk = (h * 6 + it) * 512 + tid;
                #pragma unroll
                for (int e = 0; e < 4; ++e) {
                    int sidx = chunk * 4 + e;
                    int oc = sidx / 192;
                    int r = sidx - oc * 192;
                    int ic = r / 3;
                    int tap = r - ic * 3;
                    int dst = tap * 8192 + oc * 64 + (((ic >> 3) ^ (oc & 7)) << 3) + (ic & 7);
                    st[dst] = f2bf(v[it][e]);
                }
            }
        }
        __syncthreads();
        u32x4* dst4 = (u32x4*)(wc2 + (size_t)l * 24576);
        const u32x4* s4 = (const u32x4*)st;
        #pragma unroll
        for (int it = 0; it < 6; ++it)
            dst4[it * 512 + tid] = s4[it * 512 + tid];
    } else if (blk < 60) {
        // ---- wr2: same treatment ----
        int l = blk - 30;
        unsigned short* st = (unsigned short*)smem;   // 8192 bf16 = 16KB
        const f32x4* src4 = (const f32x4*)(rs_w + (size_t)l * 8192);
        f32x4 v[4];
        #pragma unroll
        for (int it = 0; it < 4; ++it)
            v[it] = src4[it * 512 + tid];
        #pragma unroll
        for (int it = 0; it < 4; ++it) {
            int chunk = it * 512 + tid;
            #pragma unroll
            for (int e = 0; e < 4; ++e) {
                int sidx = chunk * 4 + e;
                int row = sidx >> 6;
                int ic = sidx & 63;
                int dst = row * 64 + (((ic >> 3) ^ (row & 7)) << 3) + (ic & 7);
                st[dst] = f2bf(v[it][e]);
            }
        }
        __syncthreads();
        u32x4* dst4 = (u32x4*)(wr2 + (size_t)l * 8192);
        const u32x4* s4 = (const u32x4*)st;
        #pragma unroll
        for (int it = 0; it < 2; ++it)
            dst4[it * 512 + tid] = s4[it * 512 + tid];
    } else if (blk == 60) {
        // ---- skw16 / oww16 ----
        for (int j = tid; j < 4096; j += 512)
            skw16[j] = f2bf(skip_w[j] * 0.18257418583505536f);
        for (int j = tid; j < 5120; j += 512)
            oww16[j] = f2bf(out_w[j]);
    } else {
        // ---- input conv 80->64 + transpose to (B,T,64) bf16; 256 pos/block ----
        float (*wT)[64] = (float(*)[64])smem;
        for (int i = tid; i < NM * 64; i += 512) {
            int m = i >> 6, c = i & 63;
            wT[m][c] = in_w[c * NM + m];
        }
        __syncthreads();
        int j = blk - 61;
        int b = j >> 5;
        int t = (j & 31) * 256 + (tid >> 1);
        int ch0 = (tid & 1) * 32;
        const float* xp = x + (size_t)b * NM * Tx + t;
        float acc[32];
        #pragma unroll
        for (int c = 0; c < 32; ++c) acc[c] = in_b[ch0 + c];
        #pragma unroll 1
        for (int m0 = 0; m0 < NM; m0 += 8) {
            float xv[8];
            #pragma unroll
            for (int u = 0; u < 8; ++u) xv[u] = xp[(size_t)(m0 + u) * Tx];
            #pragma unroll
            for (int u = 0; u < 8; ++u) {
                #pragma unroll
                for (int c = 0; c < 32; ++c)
                    acc[c] = fmaf(xv[u], wT[m0 + u][ch0 + c], acc[c]);
            }
        }
        unsigned short* hp = h0 + ((size_t)b * Tx + t) * 64 + ch0;
        #pragma unroll
        for (int c = 0; c < 32; c += 2) {
            unsigned int p = (unsigned int)f2bf(acc[c]) | ((unsigned int)f2bf(acc[c + 1]) << 16);
            *(unsigned int*)(hp + c) = p;
        }
    }
}

// ---------------- gbias (te recomputed per block) ----------------
// block = (l,b): phase A recomputes te[b] (131K FMA) in LDS; phase B projects.
__global__ __launch_bounds__(512) void gbias_kernel(
        const int* __restrict__ tin,
        const float* __restrict__ w1, const float* __restrict__ b1,
        const float* __restrict__ w2, const float* __restrict__ b2,
        const float* __restrict__ cemb,
        const float* __restrict__ tpw, const float* __restrict__ tpb,
        const float* __restrict__ cpw, const float* __restrict__ cpb,
        const float* __restrict__ dcb,
        float* __restrict__ gbias) {
    __shared__ float emb[128];
    __shared__ float h1s[512];
    __shared__ float red[512];
    __shared__ float ted[128];
    int l = blockIdx.x >> 3;
    int b = blockIdx.x & 7;
    int tid = threadIdx.x, wid = tid >> 6, lane = tid & 63;

    // phase A: time embedding MLP for batch b
    if (tid < 64) {
        float fr = expf(-(float)tid * (logf(10000.f) / 63.f));
        float ang = (float)tin[b] * fr;
        emb[tid] = sinf(ang);
        emb[tid + 64] = cosf(ang);
    }
    __syncthreads();
    {
        float a = b1[tid];
        const f32x4* wr4 = (const f32x4*)(w1 + tid * 128);
        #pragma unroll 8
        for (int k = 0; k < 32; ++k) {
            f32x4 w4 = wr4[k];
            a = fmaf(emb[k * 4], w4[0], a);
            a = fmaf(emb[k * 4 + 1], w4[1], a);
            a = fmaf(emb[k * 4 + 2], w4[2], a);
            a = fmaf(emb[k * 4 + 3], w4[3], a);
        }
        float sp = (a > 15.f) ? a : log1pf(expf(a));
        h1s[tid] = a * tanhf(sp);
    }
    __syncthreads();
    {
        int o = tid & 127, q = tid >> 7;
        float p = 0.f;
        const f32x4* wr4 = (const f32x4*)(w2 + o * 512 + q * 128);
        const float* hq = h1s + q * 128;
        #pragma unroll 8
        for (int k = 0; k < 32; ++k) {
            f32x4 w4 = wr4[k];
            p = fmaf(hq[k * 4], w4[0], p);
            p = fmaf(hq[k * 4 + 1], w4[1], p);
            p = fmaf(hq[k * 4 + 2], w4[2], p);
            p = fmaf(hq[k * 4 + 3], w4[3], p);
        }
        red[tid] = p;
    }
    __syncthreads();
    if (tid < 128)
        ted[tid] = b2[tid] + red[tid] + red[tid + 128] + red[tid + 256] + red[tid + 384];
    __syncthreads();

    // phase B: projections
    float te0 = ted[lane];
    float te1 = ted[64 + lane];
    float ce0 = cemb[b * 256 + lane];
    float ce1 = cemb[b * 256 + 64 + lane];
    float ce2 = cemb[b * 256 + 128 + lane];
    float ce3 = cemb[b * 256 + 192 + lane];
    #pragma unroll 4
    for (int i = 0; i < 16; ++i) {
        int ch = i * 8 + wid;
        const float* wr = tpw + (size_t)(l * 128 + ch) * 128;
        float s = te0 * wr[lane] + te1 * wr[lane + 64];
        const float* wc = cpw + (size_t)(l * 128 + ch) * 256;
        float sc = ce0 * wc[lane] + ce1 * wc[lane + 64] + ce2 * wc[lane + 128] + ce3 * wc[lane + 192];
        #pragma unroll
        for (int off = 32; off >= 1; off >>= 1) {
            s += __shfl_xor(s, off, 64);
            sc += __shfl_xor(sc, off, 64);
        }
        if (lane == 0) {
            float tp = tpb[l * 128 + ch] + s;
            float cp = cpb[l * 128 + ch] + sc;
            float s1 = tp / fmaxf(fabsf(tp), 1e-12f);
            float s2 = cp / fmaxf(fabsf(cp), 1e-12f);
            gbias[(l * 8 + b) * 128 + ch] = dcb[l * 128 + ch] + s1 + s2;
        }
    }
}

// ---------------- fused residual layer (layers 0..28) ----------------
// 8 waves; wave = M128 out-ch x N16 positions. Grid 512 = 2 blocks/CU.
// h_old*sqrt(2) and skips_old folded into rs accumulator init.
__launch_bounds__(512, 4)
__global__ void layer_kernel(const unsigned short* __restrict__ h_in,
                             unsigned short* __restrict__ h_out,
                             float* __restrict__ skips,
                             const unsigned short* __restrict__ wc2,  // pre-swizzled
                             const unsigned short* __restrict__ wr2,  // pre-swizzled
                             const float* __restrict__ gbias,         // [8][128]
                             const float* __restrict__ rsb,           // [128]
                             int dil, int first) {
    __shared__ __align__(16) unsigned char lds[81920];
    unsigned char* ldsA = lds;            // 48KB conv weights
    unsigned char* ldsR = lds + 49152;    // 16KB rs weights
    unsigned char* ldsO = lds + 65536;    // 16KB out exchange (2KB/wave)

    int tid = threadIdx.x;
    int wid = tid >> 6, lane = tid & 63, lr = lane & 15, lq = lane >> 4;

    #pragma unroll
    for (int j = 0; j < 6; ++j) {
        int cbase = j * 512 + wid * 64;
        gll16(wc2 + (size_t)(cbase + lane) * 8, ldsA + cbase * 16);
    }
    #pragma unroll
    for (int j = 0; j < 2; ++j) {
        int cbase = j * 512 + wid * 64;
        gll16(wr2 + (size_t)(cbase + lane) * 8, ldsR + cbase * 16);
    }

    int bid = blockIdx.x;
    int wg = (bid & 7) * 64 + (bid >> 3);   // batch k -> XCD k
    int b = wg >> 6;
    int t0 = ((wg & 63) << 7) + wid * 16;

    const unsigned short* hb = h_in + (size_t)b * Tx * 64;
    short8 bv[3][2];
    #pragma unroll
    for (int tap = 0; tap < 3; ++tap) {
        int toff = (tap - 1) * dil;
        int t = t0 + lr + toff;
        bool v = ((unsigned)t < (unsigned)Tx);
        #pragma unroll
        for (int kc = 0; kc < 2; ++kc) {
            short8 z = {0, 0, 0, 0, 0, 0, 0, 0};
            if (v) z = *(const short8*)(hb + t * 64 + kc * 32 + lq * 8);
            bv[tap][kc] = z;
        }
    }

    f32x4 acc[8];
    #pragma unroll
    for (int mf = 0; mf < 8; ++mf)
        acc[mf] = *(const f32x4*)(gbias + b * 128 + mf * 16 + lq * 4);
    __syncthreads();   // weights staged

    #pragma unroll
    for (int tap = 0; tap < 3; ++tap) {
        #pragma unroll
        for (int kc = 0; kc < 2; ++kc) {
            #pragma unroll
            for (int mf = 0; mf < 8; ++mf) {
                int row = tap * 128 + mf * 16 + lr;
                short8 af = *(const short8*)(ldsA + row * 128 + ((kc * 64 + lq * 16) ^ ((lr & 7) << 4)));
                acc[mf] = __builtin_amdgcn_mfma_f32_16x16x32_bf16(af, bv[tap][kc], acc[mf], 0, 0, 0);
            }
        }
    }

    // issue epilogue loads early (consumed at racc init, hidden under gating)
    size_t base = ((size_t)b * Tx + t0 + lr) * 64;
    u32x2 hv[4];
    f32x4 sko[4];
    #pragma unroll
    for (int mf = 0; mf < 4; ++mf) {
        hv[mf] = *(const u32x2*)(h_in + base + mf * 16 + lq * 4);
        if (!first) sko[mf] = *(const f32x4*)(skips + base + mf * 16 + lq * 4);
        else { sko[mf][0] = 0.f; sko[mf][1] = 0.f; sko[mf][2] = 0.f; sko[mf][3] = 0.f; }
    }

    // gating -> wave-private ldsO tile (16 pos x 64 ch)
    unsigned char* myO = ldsO + wid * 2048;
    #pragma unroll
    for (int mf = 0; mf < 4; ++mf) {
        int p = lr;
        unsigned short ob[4];
        #pragma unroll
        for (int r = 0; r < 4; ++r) {
            float g = acc[mf][r];
            float f = acc[mf + 4][r];
            f = fminf(f, 15.f);
            g = fminf(g, 30.f);
            float ea = __builtin_amdgcn_exp2f(f * 2.8853900817779268f);
            float eb = __builtin_amdgcn_exp2f(g * 1.4426950408889634f);
            float num = (ea - 1.f) * eb;
            float den = (ea + 1.f) * (1.f + eb);
            ob[r] = f2bf(num * __builtin_amdgcn_rcpf(den));
        }
        u32x2 pk;
        pk[0] = (unsigned int)ob[0] | ((unsigned int)ob[1] << 16);
        pk[1] = (unsigned int)ob[2] | ((unsigned int)ob[3] << 16);
        *(u32x2*)(myO + p * 128 + ((mf * 32 + lq * 8) ^ ((p & 7) << 4))) = pk;
    }

    // rs accumulators: res half folds h_old*sqrt(2); skip half folds skips_old
    const float rt2 = 1.41421356237309505f;
    f32x4 racc[8];
    #pragma unroll
    for (int mf = 0; mf < 4; ++mf) {
        f32x4 rb = *(const f32x4*)(rsb + mf * 16 + lq * 4);
        unsigned short* hp = (unsigned short*)&hv[mf];
        f32x4 r;
        #pragma unroll
        for (int r_ = 0; r_ < 4; ++r_) r[r_] = fmaf(bf2f(hp[r_]), rt2, rb[r_]);
        racc[mf] = r;
    }
    #pragma unroll
    for (int mf = 0; mf < 4; ++mf)
        racc[mf + 4] = *(const f32x4*)(rsb + 64 + mf * 16 + lq * 4) + sko[mf];

    #pragma unroll
    for (int kc = 0; kc < 2; ++kc) {
        int p = lr;
        short8 ov = *(const short8*)(myO + p * 128 + ((kc * 64 + lq * 16) ^ ((p & 7) << 4)));
        #pragma unroll
        for (int mf = 0; mf < 8; ++mf) {
            int row = mf * 16 + lr;
            short8 af = *(const short8*)(ldsR + row * 128 + ((kc * 64 + lq * 16) ^ ((lr & 7) << 4)));
            racc[mf] = __builtin_amdgcn_mfma_f32_16x16x32_bf16(af, ov, racc[mf], 0, 0, 0);
        }
    }

    // epilogue: h_out = racc*inv_s2 (bf16); skips = racc[4..7] (f32)
    const float inv_s2 = 0.70710678118654752f;
    #pragma unroll
    for (int mf = 0; mf < 4; ++mf) {
        unsigned short hnew[4];
        #pragma unroll
        for (int r = 0; r < 4; ++r)
            hnew[r] = f2bf(racc[mf][r] * inv_s2);
        u32x2 hw;
        hw[0] = (unsigned int)hnew[0] | ((unsigned int)hnew[1] << 16);
        hw[1] = (unsigned int)hnew[2] | ((unsigned int)hnew[3] << 16);
        *(u32x2*)(h_out + base + mf * 16 + lq * 4) = hw;
        *(f32x4*)(skips + base + mf * 16 + lq * 4) = racc[mf + 4];
    }
}

// ---------------- last layer (29) + fused skip_conv -> relu -> out_conv ----------------
__launch_bounds__(512, 2)
__global__ void layer_last_kernel(const unsigned short* __restrict__ h_in,
                                  const float* __restrict__ skips,
                                  const unsigned short* __restrict__ wc2,
                                  const unsigned short* __restrict__ wr2,
                                  const float* __restrict__ gbias,
                                  const float* __restrict__ rsb,
                                  const unsigned short* __restrict__ skw,  // [64][64] bf16 (isc folded)
                                  const float* __restrict__ skb,
                                  const unsigned short* __restrict__ oww,  // [80][64] bf16
                                  const float* __restrict__ obias,
                                  float* __restrict__ y,
                                  int dil) {
    __shared__ __align__(16) unsigned char lds[81920];
    unsigned char* ldsA = lds;
    unsigned char* ldsR = lds + 49152;
    unsigned char* ldsO = lds + 65536;

    int tid = threadIdx.x;
    int wid = tid >> 6, lane = tid & 63, lr = lane & 15, lq = lane >> 4;

    #pragma unroll
    for (int j = 0; j < 6; ++j) {
        int cbase = j * 512 + wid * 64;
        gll16(wc2 + (size_t)(cbase + lane) * 8, ldsA + cbase * 16);
    }
    #pragma unroll
    for (int j = 0; j < 2; ++j) {
        int cbase = j * 512 + wid * 64;
        gll16(wr2 + (size_t)(cbase + lane) * 8, ldsR + cbase * 16);
    }

    int bid = blockIdx.x;
    int wg = (bid & 7) * 64 + (bid >> 3);
    int b = wg >> 6;
    int t0 = ((wg & 63) << 7) + wid * 16;

    const unsigned short* hb = h_in + (size_t)b * Tx * 64;
    short8 bv[3][2];
    #pragma unroll
    for (int tap = 0; tap < 3; ++tap) {
        int toff = (tap - 1) * dil;
        int t = t0 + lr + toff;
        bool v = ((unsigned)t < (unsigned)Tx);
        #pragma unroll
        for (int kc = 0; kc < 2; ++kc) {
            short8 z = {0, 0, 0, 0, 0, 0, 0, 0};
            if (v) z = *(const short8*)(hb + t * 64 + kc * 32 + lq * 8);
            bv[tap][kc] = z;
        }
    }

    f32x4 acc[8];
    #pragma unroll
    for (int mf = 0; mf < 8; ++mf)
        acc[mf] = *(const f32x4*)(gbias + b * 128 + mf * 16 + lq * 4);
    __syncthreads();

    #pragma unroll
    for (int tap = 0; tap < 3; ++tap) {
        #pragma unroll
        for (int kc = 0; kc < 2; ++kc) {
            #pragma unroll
            for (int mf = 0; mf < 8; ++mf) {
                int row = tap * 128 + mf * 16 + lr;
                short8 af = *(const short8*)(ldsA + row * 128 + ((kc * 64 + lq * 16) ^ ((lr & 7) << 4)));
                acc[mf] = __builtin_amdgcn_mfma_f32_16x16x32_bf16(af, bv[tap][kc], acc[mf], 0, 0, 0);
            }
        }
    }

    size_t base = ((size_t)b * Tx + t0 + lr) * 64;
    f32x4 sko[4];
    #pragma unroll
    for (int mf = 0; mf < 4; ++mf)
        sko[mf] = *(const f32x4*)(skips + base + mf * 16 + lq * 4);

    unsigned char* myO = ldsO + wid * 2048;
    #pragma unroll
    for (int mf = 0; mf < 4; ++mf) {
        int p = lr;
        unsigned short ob[4];
        #pragma unroll
        for (int r = 0; r < 4; ++r) {
            float g = acc[mf][r];
            float f = acc[mf + 4][r];
            f = fminf(f, 15.f);
            g = fminf(g, 30.f);
            float ea = __builtin_amdgcn_exp2f(f * 2.8853900817779268f);
            float eb = __builtin_amdgcn_exp2f(g * 1.4426950408889634f);
            float num = (ea - 1.f) * eb;
            float den = (ea + 1.f) * (1.f + eb);
            ob[r] = f2bf(num * __builtin_amdgcn_rcpf(den));
        }
        u32x2 pk;
        pk[0] = (unsigned int)ob[0] | ((unsigned int)ob[1] << 16);
        pk[1] = (unsigned int)ob[2] | ((unsigned int)ob[3] << 16);
        *(u32x2*)(myO + p * 128 + ((mf * 32 + lq * 8) ^ ((p & 7) << 4))) = pk;
    }

    f32x4 racc[4];
    #pragma unroll
    for (int mf = 0; mf < 4; ++mf)
        racc[mf] = *(const f32x4*)(rsb + 64 + mf * 16 + lq * 4) + sko[mf];
    #pragma unroll
    for (int kc = 0; kc < 2; ++kc) {
        int p = lr;
        short8 ov = *(const short8*)(myO + p * 128 + ((kc * 64 + lq * 16) ^ ((p & 7) << 4)));
        #pragma unroll
        for (int mf = 0; mf < 4; ++mf) {
            int row = 64 + mf * 16 + lr;
            short8 af = *(const short8*)(ldsR + row * 128 + ((kc * 64 + lq * 16) ^ ((lr & 7) << 4)));
            racc[mf] = __builtin_amdgcn_mfma_f32_16x16x32_bf16(af, ov, racc[mf], 0, 0, 0);
        }
    }

    #pragma unroll
    for (int mf = 0; mf < 4; ++mf) {
        int p = lr;
        u32x2 pk;
        pk[0] = (unsigned int)f2bf(racc[mf][0]) | ((unsigned int)f2bf(racc[mf][1]) << 16);
        pk[1] = (unsigned int)f2bf(racc[mf][2]) | ((unsigned int)f2bf(racc[mf][3]) << 16);
        *(u32x2*)(myO + p * 128 + ((mf * 32 + lq * 8) ^ ((p & 7) << 4))) = pk;
    }

    f32x4 yacc[4];
    #pragma unroll
    for (int mf = 0; mf < 4; ++mf)
        yacc[mf] = *(const f32x4*)(skb + mf * 16 + lq * 4);
    #pragma unroll
    for (int kc = 0; kc < 2; ++kc) {
        int p = lr;
        short8 Bv = *(const short8*)(myO + p * 128 + ((kc * 64 + lq * 16) ^ ((p & 7) << 4)));
        #pragma unroll
        for (int mf = 0; mf < 4; ++mf) {
            short8 A1 = *(const short8*)(skw + (mf * 16 + lr) * 64 + kc * 32 + lq * 8);
            yacc[mf] = __builtin_amdgcn_mfma_f32_16x16x32_bf16(A1, Bv, yacc[mf], 0, 0, 0);
        }
    }
    #pragma unroll
    for (int mf = 0; mf < 4; ++mf) {
        int p = lr;
        u32x2 pk;
        pk[0] = (unsigned int)f2bf(fmaxf(yacc[mf][0], 0.f)) | ((unsigned int)f2bf(fmaxf(yacc[mf][1], 0.f)) << 16);
        pk[1] = (unsigned int)f2bf(fmaxf(yacc[mf][2], 0.f)) | ((unsigned int)f2bf(fmaxf(yacc[mf][3], 0.f)) << 16);
        *(u32x2*)(myO + p * 128 + ((mf * 32 + lq * 8) ^ ((p & 7) << 4))) = pk;
    }

    f32x4 oacc[5];
    #pragma unroll
    for (int mf = 0; mf < 5; ++mf)
        oacc[mf] = *(const f32x4*)(obias + mf * 16 + lq * 4);
    #pragma unroll
    for (int kc = 0; kc < 2; ++kc) {
        int p = lr;
        short8 B2 = *(const short8*)(myO + p * 128 + ((kc * 64 + lq * 16) ^ ((p & 7) << 4)));
        #pragma unroll
        for (int mf = 0; mf < 5; ++mf) {
            short8 A2 = *(const short8*)(oww + (mf * 16 + lr) * 64 + kc * 32 + lq * 8);
            oacc[mf] = __builtin_amdgcn_mfma_f32_16x16x32_bf16(A2, B2, oacc[mf], 0, 0, 0);
        }
    }
    int t = t0 + lr;
    #pragma unroll
    for (int mf = 0; mf < 5; ++mf) {
        #pragma unroll
        for (int r = 0; r < 4; ++r) {
            int m = mf * 16 + lq * 4 + r;
            y[((size_t)b * NM + m) * Tx + t] = oacc[mf][r];
        }
    }
}

extern "C" void kernel_launch(void* const* d_in, const int* in_sizes, int n_in,
                              void* d_out, int out_size, void* d_ws, size_t ws_size,
                              hipStream_t stream) {
    const float* x       = (const float*)d_in[0];
    const int*   tin     = (const int*)d_in[1];
    const float* c_emb   = (const float*)d_in[2];
    const float* in_w    = (const float*)d_in[3];
    const float* in_b    = (const float*)d_in[4];
    const float* te_w1   = (const float*)d_in[5];
    const float* te_b1   = (const float*)d_in[6];
    const float* te_w2   = (const float*)d_in[7];
    const float* te_b2   = (const float*)d_in[8];
    const float* dconv_w = (const float*)d_in[9];
    const float* dconv_b = (const float*)d_in[10];
    const float* tproj_w = (const float*)d_in[11];
    const float* tproj_b = (const float*)d_in[12];
    const float* cproj_w = (const float*)d_in[13];
    const float* cproj_b = (const float*)d_in[14];
    const float* rs_w    = (const float*)d_in[15];
    const float* rs_b    = (const float*)d_in[16];
    const float* skip_w  = (const float*)d_in[17];
    const float* skip_b  = (const float*)d_in[18];
    const float* out_w   = (const float*)d_in[19];
    const float* out_b   = (const float*)d_in[20];

    char* ws = (char*)d_ws;
    float* gbias          = (float*)(ws + 4096);              // 120KB -> 126976
    unsigned short* skw16 = (unsigned short*)(ws + 126976);   // 8KB  -> 135168
    unsigned short* oww16 = (unsigned short*)(ws + 135168);   // 10KB -> 145408
    unsigned short* wc2   = (unsigned short*)(ws + 145408);   // 1.40625MB -> 1619968
    unsigned short* wr2   = (unsigned short*)(ws + 1619968);  // 480KB -> 2111488
    unsigned short* h0    = (unsigned short*)(ws + 2111488);  // 8MB -> 10500096
    unsigned short* h1    = (unsigned short*)(ws + 10500096); // 8MB -> 18888704
    float* skips          = (float*)(ws + 18888704);          // 16MB -> 35665920

    setup_kernel<<<317, 512, 0, stream>>>(dconv_w, rs_w, skip_w, out_w,
                                          wc2, wr2, skw16, oww16,
                                          x, in_w, in_b, h0);
    gbias_kernel<<<240, 512, 0, stream>>>(tin, te_w1, te_b1, te_w2, te_b2,
                                          c_emb, tproj_w, tproj_b,
                                          cproj_w, cproj_b, dconv_b, gbias);

    unsigned short* hin = h0;
    unsigned short* hout = h1;
    for (int i = 0; i < NL - 1; ++i) {
        int dil = 1 << (i % 10);
        layer_kernel<<<512, 512, 0, stream>>>(hin, hout, skips,
                                              wc2 + (size_t)i * 24576,
                                              wr2 + (size_t)i * 8192,
                                              gbias + (size_t)i * 1024,
                                              rs_b + (size_t)i * 128,
                                              dil, i == 0 ? 1 : 0);
        unsigned short* tmp = hin; hin = hout; hout = tmp;
    }
    layer_last_kernel<<<512, 512, 0, stream>>>(hin, skips,
                                               wc2 + (size_t)(NL - 1) * 24576,
                                               wr2 + (size_t)(NL - 1) * 8192,
                                               gbias + (size_t)(NL - 1) * 1024,
                                               rs_b + (size_t)(NL - 1) * 128,
                                               skw16, skip_b, oww16, out_b,
                                               (float*)d_out, 1 << ((NL - 1) % 10));
}

// Round 9
// 531.830 us; speedup vs baseline: 1.0470x; 1.0470x over previous
//
#include <hip/hip_runtime.h>
#include <hip/hip_bf16.h>
#include <math.h>

#define NL 30
#define NM 80
#define Bx 8
#define Tx 8192

typedef short short8 __attribute__((ext_vector_type(8)));
typedef float f32x4 __attribute__((ext_vector_type(4)));
typedef unsigned int u32x2 __attribute__((ext_vector_type(2)));
typedef unsigned int u32x4 __attribute__((ext_vector_type(4)));

__device__ __forceinline__ float bf2f(unsigned short u) {
    union { unsigned int u; float f; } v; v.u = ((unsigned int)u) << 16; return v.f;
}
__device__ __forceinline__ unsigned short f2bf(float f) {
    union { float f; unsigned int u; } v; v.f = f;
    unsigned int r = v.u + 0x7FFFu + ((v.u >> 16) & 1u);
    return (unsigned short)(r >> 16);
}

#if defined(__has_builtin)
#if __has_builtin(__builtin_amdgcn_global_load_lds)
#define HAS_GLL 1
#endif
#endif

__device__ __forceinline__ void gll16(const void* g, void* l) {
#ifdef HAS_GLL
    __builtin_amdgcn_global_load_lds(
        (const __attribute__((address_space(1))) void*)g,
        (__attribute__((address_space(3))) void*)l, 16, 0, 0);
#else
    int lane = threadIdx.x & 63;
    *(u32x4*)((char*)l + lane * 16) = *(const u32x4*)((const char*)g + lane * 16);
#endif
}

// stage one layer's weights (48K conv + 16K rs), linear copy of pre-swizzled content
__device__ __forceinline__ void stageW(const unsigned short* __restrict__ wc,
                                       const unsigned short* __restrict__ wr,
                                       unsigned char* ldsA, unsigned char* ldsR, int tid) {
    int w = tid >> 6, lane = tid & 63;
    #pragma unroll
    for (int j = 0; j < 6; ++j) {
        int cbase = j * 512 + w * 64;
        gll16(wc + (size_t)(cbase + lane) * 8, ldsA + cbase * 16);
    }
    #pragma unroll
    for (int j = 0; j < 2; ++j) {
        int cbase = j * 512 + w * 64;
        gll16(wr + (size_t)(cbase + lane) * 8, ldsR + cbase * 16);
    }
}

// ---------------- merged setup ----------------
__global__ __launch_bounds__(512) void setup_kernel(
        const float* __restrict__ dconv_w, const float* __restrict__ rs_w,
        const float* __restrict__ skip_w, const float* __restrict__ out_w,
        unsigned short* __restrict__ wc2, unsigned short* __restrict__ wr2,
        unsigned short* __restrict__ skw16, unsigned short* __restrict__ oww16,
        const float* __restrict__ x, const float* __restrict__ in_w,
        const float* __restrict__ in_b, unsigned short* __restrict__ h0) {
    __shared__ __align__(16) unsigned char smem[49152];
    int blk = blockIdx.x;
    int tid = threadIdx.x;
    if (blk < 30) {
        int l = blk;
        unsigned short* st = (unsigned short*)smem;
        const f32x4* src4 = (const f32x4*)(dconv_w + (size_t)l * 24576);
        #pragma unroll
        for (int h = 0; h < 2; ++h) {
            f32x4 v[6];
            #pragma unroll
            for (int it = 0; it < 6; ++it)
                v[it] = src4[(h * 6 + it) * 512 + tid];
            #pragma unroll
            for (int it = 0; it < 6; ++it) {
                int chunk = (h * 6 + it) * 512 + tid;
                #pragma unroll
                for (int e = 0; e < 4; ++e) {
                    int sidx = chunk * 4 + e;
                    int oc = sidx / 192;
                    int r = sidx - oc * 192;
                    int ic = r / 3;
                    int tap = r - ic * 3;
                    int dst = tap * 8192 + oc * 64 + (((ic >> 3) ^ (oc & 7)) << 3) + (ic & 7);
                    st[dst] = f2bf(v[it][e]);
                }
            }
        }
        __syncthreads();
        u32x4* dst4 = (u32x4*)(wc2 + (size_t)l * 24576);
        const u32x4* s4 = (const u32x4*)st;
        #pragma unroll
        for (int it = 0; it < 6; ++it)
            dst4[it * 512 + tid] = s4[it * 512 + tid];
    } else if (blk < 60) {
        int l = blk - 30;
        unsigned short* st = (unsigned short*)smem;
        const f32x4* src4 = (const f32x4*)(rs_w + (size_t)l * 8192);
        f32x4 v[4];
        #pragma unroll
        for (int it = 0; it < 4; ++it)
            v[it] = src4[it * 512 + tid];
        #pragma unroll
        for (int it = 0; it < 4; ++it) {
            int chunk = it * 512 + tid;
            #pragma unroll
            for (int e = 0; e < 4; ++e) {
                int sidx = chunk * 4 + e;
                int row = sidx >> 6;
                int ic = sidx & 63;
                int dst = row * 64 + (((ic >> 3) ^ (row & 7)) << 3) + (ic & 7);
                st[dst] = f2bf(v[it][e]);
            }
        }
        __syncthreads();
        u32x4* dst4 = (u32x4*)(wr2 + (size_t)l * 8192);
        const u32x4* s4 = (const u32x4*)st;
        #pragma unroll
        for (int it = 0; it < 2; ++it)
            dst4[it * 512 + tid] = s4[it * 512 + tid];
    } else if (blk == 60) {
        for (int j = tid; j < 4096; j += 512)
            skw16[j] = f2bf(skip_w[j] * 0.18257418583505536f);
        for (int j = tid; j < 5120; j += 512)
            oww16[j] = f2bf(out_w[j]);
    } else {
        float (*wT)[64] = (float(*)[64])smem;
        for (int i = tid; i < NM * 64; i += 512) {
            int m = i >> 6, c = i & 63;
            wT[m][c] = in_w[c * NM + m];
        }
        __syncthreads();
        int j = blk - 61;
        int b = j >> 5;
        int t = (j & 31) * 256 + (tid >> 1);
        int ch0 = (tid & 1) * 32;
        const float* xp = x + (size_t)b * NM * Tx + t;
        float acc[32];
        #pragma unroll
        for (int c = 0; c < 32; ++c) acc[c] = in_b[ch0 + c];
        #pragma unroll 1
        for (int m0 = 0; m0 < NM; m0 += 8) {
            float xv[8];
            #pragma unroll
            for (int u = 0; u < 8; ++u) xv[u] = xp[(size_t)(m0 + u) * Tx];
            #pragma unroll
            for (int u = 0; u < 8; ++u) {
                #pragma unroll
                for (int c = 0; c < 32; ++c)
                    acc[c] = fmaf(xv[u], wT[m0 + u][ch0 + c], acc[c]);
            }
        }
        unsigned short* hp = h0 + ((size_t)b * Tx + t) * 64 + ch0;
        #pragma unroll
        for (int c = 0; c < 32; c += 2) {
            unsigned int p = (unsigned int)f2bf(acc[c]) | ((unsigned int)f2bf(acc[c + 1]) << 16);
            *(unsigned int*)(hp + c) = p;
        }
    }
}

// ---------------- gbias (te recomputed per block) ----------------
__global__ __launch_bounds__(512) void gbias_kernel(
        const int* __restrict__ tin,
        const float* __restrict__ w1, const float* __restrict__ b1,
        const float* __restrict__ w2, const float* __restrict__ b2,
        const float* __restrict__ cemb,
        const float* __restrict__ tpw, const float* __restrict__ tpb,
        const float* __restrict__ cpw, const float* __restrict__ cpb,
        const float* __restrict__ dcb,
        float* __restrict__ gbias) {
    __shared__ float emb[128];
    __shared__ float h1s[512];
    __shared__ float red[512];
    __shared__ float ted[128];
    int l = blockIdx.x >> 3;
    int b = blockIdx.x & 7;
    int tid = threadIdx.x, wid = tid >> 6, lane = tid & 63;

    if (tid < 64) {
        float fr = expf(-(float)tid * (logf(10000.f) / 63.f));
        float ang = (float)tin[b] * fr;
        emb[tid] = sinf(ang);
        emb[tid + 64] = cosf(ang);
    }
    __syncthreads();
    {
        float a = b1[tid];
        const f32x4* wr4 = (const f32x4*)(w1 + tid * 128);
        #pragma unroll 8
        for (int k = 0; k < 32; ++k) {
            f32x4 w4 = wr4[k];
            a = fmaf(emb[k * 4], w4[0], a);
            a = fmaf(emb[k * 4 + 1], w4[1], a);
            a = fmaf(emb[k * 4 + 2], w4[2], a);
            a = fmaf(emb[k * 4 + 3], w4[3], a);
        }
        float sp = (a > 15.f) ? a : log1pf(expf(a));
        h1s[tid] = a * tanhf(sp);
    }
    __syncthreads();
    {
        int o = tid & 127, q = tid >> 7;
        float p = 0.f;
        const f32x4* wr4 = (const f32x4*)(w2 + o * 512 + q * 128);
        const float* hq = h1s + q * 128;
        #pragma unroll 8
        for (int k = 0; k < 32; ++k) {
            f32x4 w4 = wr4[k];
            p = fmaf(hq[k * 4], w4[0], p);
            p = fmaf(hq[k * 4 + 1], w4[1], p);
            p = fmaf(hq[k * 4 + 2], w4[2], p);
            p = fmaf(hq[k * 4 + 3], w4[3], p);
        }
        red[tid] = p;
    }
    __syncthreads();
    if (tid < 128)
        ted[tid] = b2[tid] + red[tid] + red[tid + 128] + red[tid + 256] + red[tid + 384];
    __syncthreads();

    float te0 = ted[lane];
    float te1 = ted[64 + lane];
    float ce0 = cemb[b * 256 + lane];
    float ce1 = cemb[b * 256 + 64 + lane];
    float ce2 = cemb[b * 256 + 128 + lane];
    float ce3 = cemb[b * 256 + 192 + lane];
    #pragma unroll 4
    for (int i = 0; i < 16; ++i) {
        int ch = i * 8 + wid;
        const float* wr = tpw + (size_t)(l * 128 + ch) * 128;
        float s = te0 * wr[lane] + te1 * wr[lane + 64];
        const float* wc = cpw + (size_t)(l * 128 + ch) * 256;
        float sc = ce0 * wc[lane] + ce1 * wc[lane + 64] + ce2 * wc[lane + 128] + ce3 * wc[lane + 192];
        #pragma unroll
        for (int off = 32; off >= 1; off >>= 1) {
            s += __shfl_xor(s, off, 64);
            sc += __shfl_xor(sc, off, 64);
        }
        if (lane == 0) {
            float tp = tpb[l * 128 + ch] + s;
            float cp = cpb[l * 128 + ch] + sc;
            float s1 = tp / fmaxf(fabsf(tp), 1e-12f);
            float s2 = cp / fmaxf(fabsf(cp), 1e-12f);
            gbias[(l * 8 + b) * 128 + ch] = dcb[l * 128 + ch] + s1 + s2;
        }
    }
}

// ---------------- solo fused residual layer ----------------
__launch_bounds__(512, 4)
__global__ void layer_kernel(const unsigned short* __restrict__ h_in,
                             unsigned short* __restrict__ h_out,
                             float* __restrict__ skips,
                             const unsigned short* __restrict__ wc2,
                             const unsigned short* __restrict__ wr2,
                             const float* __restrict__ gbias,
                             const float* __restrict__ rsb,
                             int dil, int first) {
    __shared__ __align__(16) unsigned char lds[81920];
    unsigned char* ldsA = lds;
    unsigned char* ldsR = lds + 49152;
    unsigned char* ldsO = lds + 65536;

    int tid = threadIdx.x;
    int wid = tid >> 6, lane = tid & 63, lr = lane & 15, lq = lane >> 4;

    stageW(wc2, wr2, ldsA, ldsR, tid);

    int bid = blockIdx.x;
    int wg = (bid & 7) * 64 + (bid >> 3);
    int b = wg >> 6;
    int t0 = ((wg & 63) << 7) + wid * 16;

    const unsigned short* hb = h_in + (size_t)b * Tx * 64;
    short8 bv[3][2];
    #pragma unroll
    for (int tap = 0; tap < 3; ++tap) {
        int toff = (tap - 1) * dil;
        int t = t0 + lr + toff;
        bool v = ((unsigned)t < (unsigned)Tx);
        #pragma unroll
        for (int kc = 0; kc < 2; ++kc) {
            short8 z = {0, 0, 0, 0, 0, 0, 0, 0};
            if (v) z = *(const short8*)(hb + t * 64 + kc * 32 + lq * 8);
            bv[tap][kc] = z;
        }
    }

    f32x4 acc[8];
    #pragma unroll
    for (int mf = 0; mf < 8; ++mf)
        acc[mf] = *(const f32x4*)(gbias + b * 128 + mf * 16 + lq * 4);
    __syncthreads();

    #pragma unroll
    for (int tap = 0; tap < 3; ++tap) {
        #pragma unroll
        for (int kc = 0; kc < 2; ++kc) {
            #pragma unroll
            for (int mf = 0; mf < 8; ++mf) {
                int row = tap * 128 + mf * 16 + lr;
                short8 af = *(const short8*)(ldsA + row * 128 + ((kc * 64 + lq * 16) ^ ((lr & 7) << 4)));
                acc[mf] = __builtin_amdgcn_mfma_f32_16x16x32_bf16(af, bv[tap][kc], acc[mf], 0, 0, 0);
            }
        }
    }

    size_t base = ((size_t)b * Tx + t0 + lr) * 64;
    u32x2 hv[4];
    f32x4 sko[4];
    #pragma unroll
    for (int mf = 0; mf < 4; ++mf) {
        hv[mf] = *(const u32x2*)(h_in + base + mf * 16 + lq * 4);
        if (!first) sko[mf] = *(const f32x4*)(skips + base + mf * 16 + lq * 4);
        else { sko[mf][0] = 0.f; sko[mf][1] = 0.f; sko[mf][2] = 0.f; sko[mf][3] = 0.f; }
    }

    unsigned char* myO = ldsO + wid * 2048;
    #pragma unroll
    for (int mf = 0; mf < 4; ++mf) {
        int p = lr;
        unsigned short ob[4];
        #pragma unroll
        for (int r = 0; r < 4; ++r) {
            float g = acc[mf][r];
            float f = acc[mf + 4][r];
            f = fminf(f, 15.f);
            g = fminf(g, 30.f);
            float ea = __builtin_amdgcn_exp2f(f * 2.8853900817779268f);
            float eb = __builtin_amdgcn_exp2f(g * 1.4426950408889634f);
            float num = (ea - 1.f) * eb;
            float den = (ea + 1.f) * (1.f + eb);
            ob[r] = f2bf(num * __builtin_amdgcn_rcpf(den));
        }
        u32x2 pk;
        pk[0] = (unsigned int)ob[0] | ((unsigned int)ob[1] << 16);
        pk[1] = (unsigned int)ob[2] | ((unsigned int)ob[3] << 16);
        *(u32x2*)(myO + p * 128 + ((mf * 32 + lq * 8) ^ ((p & 7) << 4))) = pk;
    }

    const float rt2 = 1.41421356237309505f;
    f32x4 racc[8];
    #pragma unroll
    for (int mf = 0; mf < 4; ++mf) {
        f32x4 rb = *(const f32x4*)(rsb + mf * 16 + lq * 4);
        unsigned short* hp = (unsigned short*)&hv[mf];
        f32x4 r;
        #pragma unroll
        for (int r_ = 0; r_ < 4; ++r_) r[r_] = fmaf(bf2f(hp[r_]), rt2, rb[r_]);
        racc[mf] = r;
    }
    #pragma unroll
    for (int mf = 0; mf < 4; ++mf)
        racc[mf + 4] = *(const f32x4*)(rsb + 64 + mf * 16 + lq * 4) + sko[mf];

    #pragma unroll
    for (int kc = 0; kc < 2; ++kc) {
        int p = lr;
        short8 ov = *(const short8*)(myO + p * 128 + ((kc * 64 + lq * 16) ^ ((p & 7) << 4)));
        #pragma unroll
        for (int mf = 0; mf < 8; ++mf) {
            int row = mf * 16 + lr;
            short8 af = *(const short8*)(ldsR + row * 128 + ((kc * 64 + lq * 16) ^ ((lr & 7) << 4)));
            racc[mf] = __builtin_amdgcn_mfma_f32_16x16x32_bf16(af, ov, racc[mf], 0, 0, 0);
        }
    }

    const float inv_s2 = 0.70710678118654752f;
    #pragma unroll
    for (int mf = 0; mf < 4; ++mf) {
        unsigned short hnew[4];
        #pragma unroll
        for (int r = 0; r < 4; ++r)
            hnew[r] = f2bf(racc[mf][r] * inv_s2);
        u32x2 hw;
        hw[0] = (unsigned int)hnew[0] | ((unsigned int)hnew[1] << 16);
        hw[1] = (unsigned int)hnew[2] | ((unsigned int)hnew[3] << 16);
        *(u32x2*)(h_out + base + mf * 16 + lq * 4) = hw;
        *(f32x4*)(skips + base + mf * 16 + lq * 4) = racc[mf + 4];
    }
}

// ---------------- fused PAIR kernel: layers (l1, l1+1), dil2 <= 32 ----------------
// Extended tile: 128 core + 2*HT halo positions; h_{l1+1} kept in LDS (bf16,
// identical rounding to the global path); weights restaged mid-kernel;
// skip1 carried in registers -> single skips RMW per pair.
__launch_bounds__(512, 2)
__global__ void layer_pair_kernel(const unsigned short* __restrict__ h_in,
                                  unsigned short* __restrict__ h_out,
                                  float* __restrict__ skips,
                                  const unsigned short* __restrict__ wc2a,
                                  const unsigned short* __restrict__ wr2a,
                                  const float* __restrict__ gba,
                                  const float* __restrict__ rsba,
                                  int l1, int dil1, int dil2, int ht16, int first) {
    __shared__ __align__(16) unsigned char lds[114688];
    unsigned char* ldsA = lds;            // 48K conv weights (restaged)
    unsigned char* ldsR = lds + 49152;    // 16K rs weights (restaged)
    unsigned char* ldsH = lds + 65536;    // 24K h1: up to 192 rows x 128B
    unsigned char* ldsO = lds + 90112;    // 24K out exchange: 12 tiles x 2K

    int tid = threadIdx.x;
    int w = tid >> 6, lane = tid & 63, lr = lane & 15, lq = lane >> 4;
    int l2 = l1 + 1;
    const float rt2 = 1.41421356237309505f;
    const float inv_s2 = 0.70710678118654752f;

    stageW(wc2a + (size_t)l1 * 24576, wr2a + (size_t)l1 * 8192, ldsA, ldsR, tid);

    int bid = blockIdx.x;
    int wg = (bid & 7) * 64 + (bid >> 3);   // batch k -> XCD k
    int b = wg >> 6;
    int t0 = (wg & 63) << 7;
    int T = 8 + 2 * ht16;                   // total tiles (10 or 12)
    int ct = (w >= ht16) ? w : 8 + w;       // this wave's core tile

    const unsigned short* hb = h_in + (size_t)b * Tx * 64;
    const float* gb1 = gba + (size_t)(l1 * 8 + b) * 128;
    const float* rsb1 = rsba + (size_t)l1 * 128;
    __syncthreads();   // W1 staged

    // ---- pass 1: conv1 + gating per owned tile ----
    for (int k = 0; k < 2; ++k) {
        int tile = k ? 8 + w : w;
        if (k && tile >= T) break;
        int gtb = t0 + (tile - ht16) * 16;
        short8 bv[3][2];
        #pragma unroll
        for (int tap = 0; tap < 3; ++tap) {
            int t = gtb + lr + (tap - 1) * dil1;
            bool v = ((unsigned)t < (unsigned)Tx);
            #pragma unroll
            for (int kc = 0; kc < 2; ++kc) {
                short8 z = {0, 0, 0, 0, 0, 0, 0, 0};
                if (v) z = *(const short8*)(hb + t * 64 + kc * 32 + lq * 8);
                bv[tap][kc] = z;
            }
        }
        f32x4 acc[8];
        #pragma unroll
        for (int mf = 0; mf < 8; ++mf)
            acc[mf] = *(const f32x4*)(gb1 + mf * 16 + lq * 4);
        #pragma unroll
        for (int tap = 0; tap < 3; ++tap) {
            #pragma unroll
            for (int kc = 0; kc < 2; ++kc) {
                #pragma unroll
                for (int mf = 0; mf < 8; ++mf) {
                    int row = tap * 128 + mf * 16 + lr;
                    short8 af = *(const short8*)(ldsA + row * 128 + ((kc * 64 + lq * 16) ^ ((lr & 7) << 4)));
                    acc[mf] = __builtin_amdgcn_mfma_f32_16x16x32_bf16(af, bv[tap][kc], acc[mf], 0, 0, 0);
                }
            }
        }
        unsigned char* myO = ldsO + tile * 2048;
        #pragma unroll
        for (int mf = 0; mf < 4; ++mf) {
            int p = lr;
            unsigned short ob[4];
            #pragma unroll
            for (int r = 0; r < 4; ++r) {
                float g = acc[mf][r];
                float f = acc[mf + 4][r];
                f = fminf(f, 15.f);
                g = fminf(g, 30.f);
                float ea = __builtin_amdgcn_exp2f(f * 2.8853900817779268f);
                float eb = __builtin_amdgcn_exp2f(g * 1.4426950408889634f);
                float num = (ea - 1.f) * eb;
                float den = (ea + 1.f) * (1.f + eb);
                ob[r] = f2bf(num * __builtin_amdgcn_rcpf(den));
            }
            u32x2 pk;
            pk[0] = (unsigned int)ob[0] | ((unsigned int)ob[1] << 16);
            pk[1] = (unsigned int)ob[2] | ((unsigned int)ob[3] << 16);
            *(u32x2*)(myO + p * 128 + ((mf * 32 + lq * 8) ^ ((p & 7) << 4))) = pk;
        }
    }

    // ---- pass 1: rs1 per owned tile; h1 -> ldsH; keep core skip1/h1 in regs ----
    f32x4 sk1[4];
    u32x2 hn1[4];
    for (int k = 0; k < 2; ++k) {
        int tile = k ? 8 + w : w;
        if (k && tile >= T) break;
        int gtb = t0 + (tile - ht16) * 16;
        int t = gtb + lr;
        bool tv = ((unsigned)t < (unsigned)Tx);
        u32x2 hv[4];
        #pragma unroll
        for (int mf = 0; mf < 4; ++mf) {
            u32x2 z; z[0] = 0u; z[1] = 0u;
            if (tv) z = *(const u32x2*)(h_in + ((size_t)b * Tx + t) * 64 + mf * 16 + lq * 4);
            hv[mf] = z;
        }
        f32x4 racc[8];
        #pragma unroll
        for (int mf = 0; mf < 4; ++mf) {
            f32x4 rb = *(const f32x4*)(rsb1 + mf * 16 + lq * 4);
            unsigned short* hp = (unsigned short*)&hv[mf];
            f32x4 r;
            #pragma unroll
            for (int r_ = 0; r_ < 4; ++r_) r[r_] = fmaf(bf2f(hp[r_]), rt2, rb[r_]);
            racc[mf] = r;
        }
        #pragma unroll
        for (int mf = 0; mf < 4; ++mf)
            racc[mf + 4] = *(const f32x4*)(rsb1 + 64 + mf * 16 + lq * 4);
        unsigned char* myO = ldsO + tile * 2048;
        #pragma unroll
        for (int kc = 0; kc < 2; ++kc) {
            int p = lr;
            short8 ov = *(const short8*)(myO + p * 128 + ((kc * 64 + lq * 16) ^ ((p & 7) << 4)));
            #pragma unroll
            for (int mf = 0; mf < 8; ++mf) {
                int row = mf * 16 + lr;
                short8 af = *(const short8*)(ldsR + row * 128 + ((kc * 64 + lq * 16) ^ ((lr & 7) << 4)));
                racc[mf] = __builtin_amdgcn_mfma_f32_16x16x32_bf16(af, ov, racc[mf], 0, 0, 0);
            }
        }
        // h1 bf16 -> ldsH (zero rows for OOB positions)
        int hrow = tile * 16 + lr;
        #pragma unroll
        for (int mf = 0; mf < 4; ++mf) {
            u32x2 pk; pk[0] = 0u; pk[1] = 0u;
            if (tv) {
                unsigned short hn[4];
                #pragma unroll
                for (int r = 0; r < 4; ++r)
                    hn[r] = f2bf(racc[mf][r] * inv_s2);
                pk[0] = (unsigned int)hn[0] | ((unsigned int)hn[1] << 16);
                pk[1] = (unsigned int)hn[2] | ((unsigned int)hn[3] << 16);
            }
            *(u32x2*)(ldsH + hrow * 128 + ((mf * 32 + lq * 8) ^ ((hrow & 7) << 4))) = pk;
            if (tile == ct) { sk1[mf] = racc[mf + 4]; hn1[mf] = pk; }
        }
    }
    __syncthreads();   // W1 consumed by all, h1 complete

    // ---- stage W2 + prefetch pass-2 operands ----
    stageW(wc2a + (size_t)l2 * 24576, wr2a + (size_t)l2 * 8192, ldsA, ldsR, tid);
    int gtc = t0 + (ct - ht16) * 16;
    size_t cbase = ((size_t)b * Tx + gtc + lr) * 64;
    f32x4 sko[4];
    #pragma unroll
    for (int mf = 0; mf < 4; ++mf) {
        if (!first) sko[mf] = *(const f32x4*)(skips + cbase + mf * 16 + lq * 4);
        else { sko[mf][0] = 0.f; sko[mf][1] = 0.f; sko[mf][2] = 0.f; sko[mf][3] = 0.f; }
    }
    const float* gb2 = gba + (size_t)(l2 * 8 + b) * 128;
    const float* rsb2 = rsba + (size_t)l2 * 128;
    f32x4 acc2[8];
    #pragma unroll
    for (int mf = 0; mf < 8; ++mf)
        acc2[mf] = *(const f32x4*)(gb2 + mf * 16 + lq * 4);
    __syncthreads();   // W2 staged

    // ---- pass 2: conv2 (B from ldsH) for core tile ----
    int lrow0 = ct * 16 + lr;
    #pragma unroll
    for (int tap = 0; tap < 3; ++tap) {
        int row = lrow0 + (tap - 1) * dil2;
        #pragma unroll
        for (int kc = 0; kc < 2; ++kc) {
            short8 bv2 = *(const short8*)(ldsH + row * 128 + ((kc * 64 + lq * 16) ^ ((row & 7) << 4)));
            #pragma unroll
            for (int mf = 0; mf < 8; ++mf) {
                int wrow = tap * 128 + mf * 16 + lr;
                short8 af = *(const short8*)(ldsA + wrow * 128 + ((kc * 64 + lq * 16) ^ ((lr & 7) << 4)));
                acc2[mf] = __builtin_amdgcn_mfma_f32_16x16x32_bf16(af, bv2, acc2[mf], 0, 0, 0);
            }
        }
    }

    // gating 2 -> ldsO[ct]
    unsigned char* myO = ldsO + ct * 2048;
    #pragma unroll
    for (int mf = 0; mf < 4; ++mf) {
        int p = lr;
        unsigned short ob[4];
        #pragma unroll
        for (int r = 0; r < 4; ++r) {
            float g = acc2[mf][r];
            float f = acc2[mf + 4][r];
            f = fminf(f, 15.f);
            g = fminf(g, 30.f);
            float ea = __builtin_amdgcn_exp2f(f * 2.8853900817779268f);
            float eb = __builtin_amdgcn_exp2f(g * 1.4426950408889634f);
            float num = (ea - 1.f) * eb;
            float den = (ea + 1.f) * (1.f + eb);
            ob[r] = f2bf(num * __builtin_amdgcn_rcpf(den));
        }
        u32x2 pk;
        pk[0] = (unsigned int)ob[0] | ((unsigned int)ob[1] << 16);
        pk[1] = (unsigned int)ob[2] | ((unsigned int)ob[3] << 16);
        *(u32x2*)(myO + p * 128 + ((mf * 32 + lq * 8) ^ ((p & 7) << 4))) = pk;
    }

    // rs2: res folds h1*sqrt(2); skip folds sko + sk1
    f32x4 racc2[8];
    #pragma unroll
    for (int mf = 0; mf < 4; ++mf) {
        f32x4 rb = *(const f32x4*)(rsb2 + mf * 16 + lq * 4);
        unsigned short* hp = (unsigned short*)&hn1[mf];
        f32x4 r;
        #pragma unroll
        for (int r_ = 0; r_ < 4; ++r_) r[r_] = fmaf(bf2f(hp[r_]), rt2, rb[r_]);
        racc2[mf] = r;
    }
    #pragma unroll
    for (int mf = 0; mf < 4; ++mf)
        racc2[mf + 4] = *(const f32x4*)(rsb2 + 64 + mf * 16 + lq * 4) + sko[mf] + sk1[mf];

    #pragma unroll
    for (int kc = 0; kc < 2; ++kc) {
        int p = lr;
        short8 ov = *(const short8*)(myO + p * 128 + ((kc * 64 + lq * 16) ^ ((p & 7) << 4)));
        #pragma unroll
        for (int mf = 0; mf < 8; ++mf) {
            int row = mf * 16 + lr;
            short8 af = *(const short8*)(ldsR + row * 128 + ((kc * 64 + lq * 16) ^ ((lr & 7) << 4)));
            racc2[mf] = __builtin_amdgcn_mfma_f32_16x16x32_bf16(af, ov, racc2[mf], 0, 0, 0);
        }
    }

    // epilogue: h_out(core) bf16; skips(core) f32 (single RMW for the pair)
    #pragma unroll
    for (int mf = 0; mf < 4; ++mf) {
        unsigned short hnew[4];
        #pragma unroll
        for (int r = 0; r < 4; ++r)
            hnew[r] = f2bf(racc2[mf][r] * inv_s2);
        u32x2 hw;
        hw[0] = (unsigned int)hnew[0] | ((unsigned int)hnew[1] << 16);
        hw[1] = (unsigned int)hnew[2] | ((unsigned int)hnew[3] << 16);
        *(u32x2*)(h_out + cbase + mf * 16 + lq * 4) = hw;
        *(f32x4*)(skips + cbase + mf * 16 + lq * 4) = racc2[mf + 4];
    }
}

// ---------------- last layer (29) + fused skip_conv -> relu -> out_conv ----------------
__launch_bounds__(512, 2)
__global__ void layer_last_kernel(const unsigned short* __restrict__ h_in,
                                  const float* __restrict__ skips,
                                  const unsigned short* __restrict__ wc2,
                                  const unsigned short* __restrict__ wr2,
                                  const float* __restrict__ gbias,
                                  const float* __restrict__ rsb,
                                  const unsigned short* __restrict__ skw,
                                  const float* __restrict__ skb,
                                  const unsigned short* __restrict__ oww,
                                  const float* __restrict__ obias,
                                  float* __restrict__ y,
                                  int dil) {
    __shared__ __align__(16) unsigned char lds[81920];
    unsigned char* ldsA = lds;
    unsigned char* ldsR = lds + 49152;
    unsigned char* ldsO = lds + 65536;

    int tid = threadIdx.x;
    int wid = tid >> 6, lane = tid & 63, lr = lane & 15, lq = lane >> 4;

    stageW(wc2, wr2, ldsA, ldsR, tid);

    int bid = blockIdx.x;
    int wg = (bid & 7) * 64 + (bid >> 3);
    int b = wg >> 6;
    int t0 = ((wg & 63) << 7) + wid * 16;

    const unsigned short* hb = h_in + (size_t)b * Tx * 64;
    short8 bv[3][2];
    #pragma unroll
    for (int tap = 0; tap < 3; ++tap) {
        int toff = (tap - 1) * dil;
        int t = t0 + lr + toff;
        bool v = ((unsigned)t < (unsigned)Tx);
        #pragma unroll
        for (int kc = 0; kc < 2; ++kc) {
            short8 z = {0, 0, 0, 0, 0, 0, 0, 0};
            if (v) z = *(const short8*)(hb + t * 64 + kc * 32 + lq * 8);
            bv[tap][kc] = z;
        }
    }

    f32x4 acc[8];
    #pragma unroll
    for (int mf = 0; mf < 8; ++mf)
        acc[mf] = *(const f32x4*)(gbias + b * 128 + mf * 16 + lq * 4);
    __syncthreads();

    #pragma unroll
    for (int tap = 0; tap < 3; ++tap) {
        #pragma unroll
        for (int kc = 0; kc < 2; ++kc) {
            #pragma unroll
            for (int mf = 0; mf < 8; ++mf) {
                int row = tap * 128 + mf * 16 + lr;
                short8 af = *(const short8*)(ldsA + row * 128 + ((kc * 64 + lq * 16) ^ ((lr & 7) << 4)));
                acc[mf] = __builtin_amdgcn_mfma_f32_16x16x32_bf16(af, bv[tap][kc], acc[mf], 0, 0, 0);
            }
        }
    }

    size_t base = ((size_t)b * Tx + t0 + lr) * 64;
    f32x4 sko[4];
    #pragma unroll
    for (int mf = 0; mf < 4; ++mf)
        sko[mf] = *(const f32x4*)(skips + base + mf * 16 + lq * 4);

    unsigned char* myO = ldsO + wid * 2048;
    #pragma unroll
    for (int mf = 0; mf < 4; ++mf) {
        int p = lr;
        unsigned short ob[4];
        #pragma unroll
        for (int r = 0; r < 4; ++r) {
            float g = acc[mf][r];
            float f = acc[mf + 4][r];
            f = fminf(f, 15.f);
            g = fminf(g, 30.f);
            float ea = __builtin_amdgcn_exp2f(f * 2.8853900817779268f);
            float eb = __builtin_amdgcn_exp2f(g * 1.4426950408889634f);
            float num = (ea - 1.f) * eb;
            float den = (ea + 1.f) * (1.f + eb);
            ob[r] = f2bf(num * __builtin_amdgcn_rcpf(den));
        }
        u32x2 pk;
        pk[0] = (unsigned int)ob[0] | ((unsigned int)ob[1] << 16);
        pk[1] = (unsigned int)ob[2] | ((unsigned int)ob[3] << 16);
        *(u32x2*)(myO + p * 128 + ((mf * 32 + lq * 8) ^ ((p & 7) << 4))) = pk;
    }

    f32x4 racc[4];
    #pragma unroll
    for (int mf = 0; mf < 4; ++mf)
        racc[mf] = *(const f32x4*)(rsb + 64 + mf * 16 + lq * 4) + sko[mf];
    #pragma unroll
    for (int kc = 0; kc < 2; ++kc) {
        int p = lr;
        short8 ov = *(const short8*)(myO + p * 128 + ((kc * 64 + lq * 16) ^ ((p & 7) << 4)));
        #pragma unroll
        for (int mf = 0; mf < 4; ++mf) {
            int row = 64 + mf * 16 + lr;
            short8 af = *(const short8*)(ldsR + row * 128 + ((kc * 64 + lq * 16) ^ ((lr & 7) << 4)));
            racc[mf] = __builtin_amdgcn_mfma_f32_16x16x32_bf16(af, ov, racc[mf], 0, 0, 0);
        }
    }

    #pragma unroll
    for (int mf = 0; mf < 4; ++mf) {
        int p = lr;
        u32x2 pk;
        pk[0] = (unsigned int)f2bf(racc[mf][0]) | ((unsigned int)f2bf(racc[mf][1]) << 16);
        pk[1] = (unsigned int)f2bf(racc[mf][2]) | ((unsigned int)f2bf(racc[mf][3]) << 16);
        *(u32x2*)(myO + p * 128 + ((mf * 32 + lq * 8) ^ ((p & 7) << 4))) = pk;
    }

    f32x4 yacc[4];
    #pragma unroll
    for (int mf = 0; mf < 4; ++mf)
        yacc[mf] = *(const f32x4*)(skb + mf * 16 + lq * 4);
    #pragma unroll
    for (int kc = 0; kc < 2; ++kc) {
        int p = lr;
        short8 Bv = *(const short8*)(myO + p * 128 + ((kc * 64 + lq * 16) ^ ((p & 7) << 4)));
        #pragma unroll
        for (int mf = 0; mf < 4; ++mf) {
            short8 A1 = *(const short8*)(skw + (mf * 16 + lr) * 64 + kc * 32 + lq * 8);
            yacc[mf] = __builtin_amdgcn_mfma_f32_16x16x32_bf16(A1, Bv, yacc[mf], 0, 0, 0);
        }
    }
    #pragma unroll
    for (int mf = 0; mf < 4; ++mf) {
        int p = lr;
        u32x2 pk;
        pk[0] = (unsigned int)f2bf(fmaxf(yacc[mf][0], 0.f)) | ((unsigned int)f2bf(fmaxf(yacc[mf][1], 0.f)) << 16);
        pk[1] = (unsigned int)f2bf(fmaxf(yacc[mf][2], 0.f)) | ((unsigned int)f2bf(fmaxf(yacc[mf][3], 0.f)) << 16);
        *(u32x2*)(myO + p * 128 + ((mf * 32 + lq * 8) ^ ((p & 7) << 4))) = pk;
    }

    f32x4 oacc[5];
    #pragma unroll
    for (int mf = 0; mf < 5; ++mf)
        oacc[mf] = *(const f32x4*)(obias + mf * 16 + lq * 4);
    #pragma unroll
    for (int kc = 0; kc < 2; ++kc) {
        int p = lr;
        short8 B2 = *(const short8*)(myO + p * 128 + ((kc * 64 + lq * 16) ^ ((p & 7) << 4)));
        #pragma unroll
        for (int mf = 0; mf < 5; ++mf) {
            short8 A2 = *(const short8*)(oww + (mf * 16 + lr) * 64 + kc * 32 + lq * 8);
            oacc[mf] = __builtin_amdgcn_mfma_f32_16x16x32_bf16(A2, B2, oacc[mf], 0, 0, 0);
        }
    }
    int t = t0 + lr;
    #pragma unroll
    for (int mf = 0; mf < 5; ++mf) {
        #pragma unroll
        for (int r = 0; r < 4; ++r) {
            int m = mf * 16 + lq * 4 + r;
            y[((size_t)b * NM + m) * Tx + t] = oacc[mf][r];
        }
    }
}

extern "C" void kernel_launch(void* const* d_in, const int* in_sizes, int n_in,
                              void* d_out, int out_size, void* d_ws, size_t ws_size,
                              hipStream_t stream) {
    const float* x       = (const float*)d_in[0];
    const int*   tin     = (const int*)d_in[1];
    const float* c_emb   = (const float*)d_in[2];
    const float* in_w    = (const float*)d_in[3];
    const float* in_b    = (const float*)d_in[4];
    const float* te_w1   = (const float*)d_in[5];
    const float* te_b1   = (const float*)d_in[6];
    const float* te_w2   = (const float*)d_in[7];
    const float* te_b2   = (const float*)d_in[8];
    const float* dconv_w = (const float*)d_in[9];
    const float* dconv_b = (const float*)d_in[10];
    const float* tproj_w = (const float*)d_in[11];
    const float* tproj_b = (const float*)d_in[12];
    const float* cproj_w = (const float*)d_in[13];
    const float* cproj_b = (const float*)d_in[14];
    const float* rs_w    = (const float*)d_in[15];
    const float* rs_b    = (const float*)d_in[16];
    const float* skip_w  = (const float*)d_in[17];
    const float* skip_b  = (const float*)d_in[18];
    const float* out_w   = (const float*)d_in[19];
    const float* out_b   = (const float*)d_in[20];

    char* ws = (char*)d_ws;
    float* gbias          = (float*)(ws + 4096);
    unsigned short* skw16 = (unsigned short*)(ws + 126976);
    unsigned short* oww16 = (unsigned short*)(ws + 135168);
    unsigned short* wc2   = (unsigned short*)(ws + 145408);
    unsigned short* wr2   = (unsigned short*)(ws + 1619968);
    unsigned short* h0    = (unsigned short*)(ws + 2111488);
    unsigned short* h1    = (unsigned short*)(ws + 10500096);
    float* skips          = (float*)(ws + 18888704);

    setup_kernel<<<317, 512, 0, stream>>>(dconv_w, rs_w, skip_w, out_w,
                                          wc2, wr2, skw16, oww16,
                                          x, in_w, in_b, h0);
    gbias_kernel<<<240, 512, 0, stream>>>(tin, te_w1, te_b1, te_w2, te_b2,
                                          c_emb, tproj_w, tproj_b,
                                          cproj_w, cproj_b, dconv_b, gbias);

    // pair starts (dil_{i+1} <= 32): fuse (i, i+1); others solo; layer 29 last.
    bool pstart[29] = {false};
    pstart[0] = pstart[2] = pstart[4] = pstart[9] = pstart[11] = pstart[13]
              = pstart[19] = pstart[21] = pstart[23] = true;

    unsigned short* hin = h0;
    unsigned short* hout = h1;
    int i = 0;
    while (i < NL - 1) {
        int dil = 1 << (i % 10);
        if (pstart[i]) {
            int dil2 = 1 << ((i + 1) % 10);
            int ht16 = (dil2 > 16) ? 2 : 1;
            layer_pair_kernel<<<512, 512, 0, stream>>>(hin, hout, skips,
                                                       wc2, wr2, gbias, rs_b,
                                                       i, dil, dil2, ht16,
                                                       i == 0 ? 1 : 0);
            unsigned short* tmp = hin; hin = hout; hout = tmp;
            i += 2;
        } else {
            layer_kernel<<<512, 512, 0, stream>>>(hin, hout, skips,
                                                  wc2 + (size_t)i * 24576,
                                                  wr2 + (size_t)i * 8192,
                                                  gbias + (size_t)i * 1024,
                                                  rs_b + (size_t)i * 128,
                                                  dil, 0);
            unsigned short* tmp = hin; hin = hout; hout = tmp;
            i += 1;
        }
    }
    layer_last_kernel<<<512, 512, 0, stream>>>(hin, skips,
                                               wc2 + (size_t)(NL - 1) * 24576,
                                               wr2 + (size_t)(NL - 1) * 8192,
                                               gbias + (size_t)(NL - 1) * 1024,
                                               rs_b + (size_t)(NL - 1) * 128,
                                               skw16, skip_b, oww16, out_b,
                                               (float*)d_out, 1 << ((NL - 1) % 10));
}

// Round 10
// 517.529 us; speedup vs baseline: 1.0759x; 1.0276x over previous
//
#include <hip/hip_runtime.h>
#include <hip/hip_bf16.h>
#include <math.h>

#define NL 30
#define NM 80
#define Bx 8
#define Tx 8192

typedef short short8 __attribute__((ext_vector_type(8)));
typedef float f32x4 __attribute__((ext_vector_type(4)));
typedef unsigned int u32x2 __attribute__((ext_vector_type(2)));
typedef unsigned int u32x4 __attribute__((ext_vector_type(4)));

__device__ __forceinline__ float bf2f(unsigned short u) {
    union { unsigned int u; float f; } v; v.u = ((unsigned int)u) << 16; return v.f;
}
__device__ __forceinline__ unsigned short f2bf(float f) {
    union { float f; unsigned int u; } v; v.f = f;
    unsigned int r = v.u + 0x7FFFu + ((v.u >> 16) & 1u);
    return (unsigned short)(r >> 16);
}

#if defined(__has_builtin)
#if __has_builtin(__builtin_amdgcn_global_load_lds)
#define HAS_GLL 1
#endif
#endif

__device__ __forceinline__ void gll16(const void* g, void* l) {
#ifdef HAS_GLL
    __builtin_amdgcn_global_load_lds(
        (const __attribute__((address_space(1))) void*)g,
        (__attribute__((address_space(3))) void*)l, 16, 0, 0);
#else
    int lane = threadIdx.x & 63;
    *(u32x4*)((char*)l + lane * 16) = *(const u32x4*)((const char*)g + lane * 16);
#endif
}

// stage one layer's weights (48K conv + 16K rs), linear copy of pre-swizzled content
__device__ __forceinline__ void stageW(const unsigned short* __restrict__ wc,
                                       const unsigned short* __restrict__ wr,
                                       unsigned char* ldsA, unsigned char* ldsR, int tid) {
    int w = tid >> 6, lane = tid & 63;
    #pragma unroll
    for (int j = 0; j < 6; ++j) {
        int cbase = j * 512 + w * 64;
        gll16(wc + (size_t)(cbase + lane) * 8, ldsA + cbase * 16);
    }
    #pragma unroll
    for (int j = 0; j < 2; ++j) {
        int cbase = j * 512 + w * 64;
        gll16(wr + (size_t)(cbase + lane) * 8, ldsR + cbase * 16);
    }
}

// ---------------- merged setup ----------------
__global__ __launch_bounds__(512) void setup_kernel(
        const float* __restrict__ dconv_w, const float* __restrict__ rs_w,
        const float* __restrict__ skip_w, const float* __restrict__ out_w,
        unsigned short* __restrict__ wc2, unsigned short* __restrict__ wr2,
        unsigned short* __restrict__ skw16, unsigned short* __restrict__ oww16,
        const float* __restrict__ x, const float* __restrict__ in_w,
        const float* __restrict__ in_b, unsigned short* __restrict__ h0) {
    __shared__ __align__(16) unsigned char smem[49152];
    int blk = blockIdx.x;
    int tid = threadIdx.x;
    if (blk < 30) {
        int l = blk;
        unsigned short* st = (unsigned short*)smem;
        const f32x4* src4 = (const f32x4*)(dconv_w + (size_t)l * 24576);
        #pragma unroll
        for (int h = 0; h < 2; ++h) {
            f32x4 v[6];
            #pragma unroll
            for (int it = 0; it < 6; ++it)
                v[it] = src4[(h * 6 + it) * 512 + tid];
            #pragma unroll
            for (int it = 0; it < 6; ++it) {
                int chunk = (h * 6 + it) * 512 + tid;
                #pragma unroll
                for (int e = 0; e < 4; ++e) {
                    int sidx = chunk * 4 + e;
                    int oc = sidx / 192;
                    int r = sidx - oc * 192;
                    int ic = r / 3;
                    int tap = r - ic * 3;
                    int dst = tap * 8192 + oc * 64 + (((ic >> 3) ^ (oc & 7)) << 3) + (ic & 7);
                    st[dst] = f2bf(v[it][e]);
                }
            }
        }
        __syncthreads();
        u32x4* dst4 = (u32x4*)(wc2 + (size_t)l * 24576);
        const u32x4* s4 = (const u32x4*)st;
        #pragma unroll
        for (int it = 0; it < 6; ++it)
            dst4[it * 512 + tid] = s4[it * 512 + tid];
    } else if (blk < 60) {
        int l = blk - 30;
        unsigned short* st = (unsigned short*)smem;
        const f32x4* src4 = (const f32x4*)(rs_w + (size_t)l * 8192);
        f32x4 v[4];
        #pragma unroll
        for (int it = 0; it < 4; ++it)
            v[it] = src4[it * 512 + tid];
        #pragma unroll
        for (int it = 0; it < 4; ++it) {
            int chunk = it * 512 + tid;
            #pragma unroll
            for (int e = 0; e < 4; ++e) {
                int sidx = chunk * 4 + e;
                int row = sidx >> 6;
                int ic = sidx & 63;
                int dst = row * 64 + (((ic >> 3) ^ (row & 7)) << 3) + (ic & 7);
                st[dst] = f2bf(v[it][e]);
            }
        }
        __syncthreads();
        u32x4* dst4 = (u32x4*)(wr2 + (size_t)l * 8192);
        const u32x4* s4 = (const u32x4*)st;
        #pragma unroll
        for (int it = 0; it < 2; ++it)
            dst4[it * 512 + tid] = s4[it * 512 + tid];
    } else if (blk == 60) {
        for (int j = tid; j < 4096; j += 512)
            skw16[j] = f2bf(skip_w[j] * 0.18257418583505536f);
        for (int j = tid; j < 5120; j += 512)
            oww16[j] = f2bf(out_w[j]);
    } else {
        float (*wT)[64] = (float(*)[64])smem;
        for (int i = tid; i < NM * 64; i += 512) {
            int m = i >> 6, c = i & 63;
            wT[m][c] = in_w[c * NM + m];
        }
        __syncthreads();
        int j = blk - 61;
        int b = j >> 5;
        int t = (j & 31) * 256 + (tid >> 1);
        int ch0 = (tid & 1) * 32;
        const float* xp = x + (size_t)b * NM * Tx + t;
        float acc[32];
        #pragma unroll
        for (int c = 0; c < 32; ++c) acc[c] = in_b[ch0 + c];
        #pragma unroll 1
        for (int m0 = 0; m0 < NM; m0 += 8) {
            float xv[8];
            #pragma unroll
            for (int u = 0; u < 8; ++u) xv[u] = xp[(size_t)(m0 + u) * Tx];
            #pragma unroll
            for (int u = 0; u < 8; ++u) {
                #pragma unroll
                for (int c = 0; c < 32; ++c)
                    acc[c] = fmaf(xv[u], wT[m0 + u][ch0 + c], acc[c]);
            }
        }
        unsigned short* hp = h0 + ((size_t)b * Tx + t) * 64 + ch0;
        #pragma unroll
        for (int c = 0; c < 32; c += 2) {
            unsigned int p = (unsigned int)f2bf(acc[c]) | ((unsigned int)f2bf(acc[c + 1]) << 16);
            *(unsigned int*)(hp + c) = p;
        }
    }
}

// ---------------- gbias (te recomputed per block) ----------------
__global__ __launch_bounds__(512) void gbias_kernel(
        const int* __restrict__ tin,
        const float* __restrict__ w1, const float* __restrict__ b1,
        const float* __restrict__ w2, const float* __restrict__ b2,
        const float* __restrict__ cemb,
        const float* __restrict__ tpw, const float* __restrict__ tpb,
        const float* __restrict__ cpw, const float* __restrict__ cpb,
        const float* __restrict__ dcb,
        float* __restrict__ gbias) {
    __shared__ float emb[128];
    __shared__ float h1s[512];
    __shared__ float red[512];
    __shared__ float ted[128];
    int l = blockIdx.x >> 3;
    int b = blockIdx.x & 7;
    int tid = threadIdx.x, wid = tid >> 6, lane = tid & 63;

    if (tid < 64) {
        float fr = expf(-(float)tid * (logf(10000.f) / 63.f));
        float ang = (float)tin[b] * fr;
        emb[tid] = sinf(ang);
        emb[tid + 64] = cosf(ang);
    }
    __syncthreads();
    {
        float a = b1[tid];
        const f32x4* wr4 = (const f32x4*)(w1 + tid * 128);
        #pragma unroll 8
        for (int k = 0; k < 32; ++k) {
            f32x4 w4 = wr4[k];
            a = fmaf(emb[k * 4], w4[0], a);
            a = fmaf(emb[k * 4 + 1], w4[1], a);
            a = fmaf(emb[k * 4 + 2], w4[2], a);
            a = fmaf(emb[k * 4 + 3], w4[3], a);
        }
        float sp = (a > 15.f) ? a : log1pf(expf(a));
        h1s[tid] = a * tanhf(sp);
    }
    __syncthreads();
    {
        int o = tid & 127, q = tid >> 7;
        float p = 0.f;
        const f32x4* wr4 = (const f32x4*)(w2 + o * 512 + q * 128);
        const float* hq = h1s + q * 128;
        #pragma unroll 8
        for (int k = 0; k < 32; ++k) {
            f32x4 w4 = wr4[k];
            p = fmaf(hq[k * 4], w4[0], p);
            p = fmaf(hq[k * 4 + 1], w4[1], p);
            p = fmaf(hq[k * 4 + 2], w4[2], p);
            p = fmaf(hq[k * 4 + 3], w4[3], p);
        }
        red[tid] = p;
    }
    __syncthreads();
    if (tid < 128)
        ted[tid] = b2[tid] + red[tid] + red[tid + 128] + red[tid + 256] + red[tid + 384];
    __syncthreads();

    float te0 = ted[lane];
    float te1 = ted[64 + lane];
    float ce0 = cemb[b * 256 + lane];
    float ce1 = cemb[b * 256 + 64 + lane];
    float ce2 = cemb[b * 256 + 128 + lane];
    float ce3 = cemb[b * 256 + 192 + lane];
    #pragma unroll 4
    for (int i = 0; i < 16; ++i) {
        int ch = i * 8 + wid;
        const float* wr = tpw + (size_t)(l * 128 + ch) * 128;
        float s = te0 * wr[lane] + te1 * wr[lane + 64];
        const float* wc = cpw + (size_t)(l * 128 + ch) * 256;
        float sc = ce0 * wc[lane] + ce1 * wc[lane + 64] + ce2 * wc[lane + 128] + ce3 * wc[lane + 192];
        #pragma unroll
        for (int off = 32; off >= 1; off >>= 1) {
            s += __shfl_xor(s, off, 64);
            sc += __shfl_xor(sc, off, 64);
        }
        if (lane == 0) {
            float tp = tpb[l * 128 + ch] + s;
            float cp = cpb[l * 128 + ch] + sc;
            float s1 = tp / fmaxf(fabsf(tp), 1e-12f);
            float s2 = cp / fmaxf(fabsf(cp), 1e-12f);
            gbias[(l * 8 + b) * 128 + ch] = dcb[l * 128 + ch] + s1 + s2;
        }
    }
}

// ---------------- solo fused residual layer ----------------
__launch_bounds__(512, 4)
__global__ void layer_kernel(const unsigned short* __restrict__ h_in,
                             unsigned short* __restrict__ h_out,
                             float* __restrict__ skips,
                             const unsigned short* __restrict__ wc2,
                             const unsigned short* __restrict__ wr2,
                             const float* __restrict__ gbias,
                             const float* __restrict__ rsb,
                             int dil, int first) {
    __shared__ __align__(16) unsigned char lds[81920];
    unsigned char* ldsA = lds;
    unsigned char* ldsR = lds + 49152;
    unsigned char* ldsO = lds + 65536;

    int tid = threadIdx.x;
    int wid = tid >> 6, lane = tid & 63, lr = lane & 15, lq = lane >> 4;

    stageW(wc2, wr2, ldsA, ldsR, tid);

    int bid = blockIdx.x;
    int wg = (bid & 7) * 64 + (bid >> 3);
    int b = wg >> 6;
    int t0 = ((wg & 63) << 7) + wid * 16;

    const unsigned short* hb = h_in + (size_t)b * Tx * 64;
    short8 bv[3][2];
    #pragma unroll
    for (int tap = 0; tap < 3; ++tap) {
        int toff = (tap - 1) * dil;
        int t = t0 + lr + toff;
        bool v = ((unsigned)t < (unsigned)Tx);
        #pragma unroll
        for (int kc = 0; kc < 2; ++kc) {
            short8 z = {0, 0, 0, 0, 0, 0, 0, 0};
            if (v) z = *(const short8*)(hb + t * 64 + kc * 32 + lq * 8);
            bv[tap][kc] = z;
        }
    }

    f32x4 acc[8];
    #pragma unroll
    for (int mf = 0; mf < 8; ++mf)
        acc[mf] = *(const f32x4*)(gbias + b * 128 + mf * 16 + lq * 4);
    __syncthreads();

    #pragma unroll
    for (int tap = 0; tap < 3; ++tap) {
        #pragma unroll
        for (int kc = 0; kc < 2; ++kc) {
            #pragma unroll
            for (int mf = 0; mf < 8; ++mf) {
                int row = tap * 128 + mf * 16 + lr;
                short8 af = *(const short8*)(ldsA + row * 128 + ((kc * 64 + lq * 16) ^ ((lr & 7) << 4)));
                acc[mf] = __builtin_amdgcn_mfma_f32_16x16x32_bf16(af, bv[tap][kc], acc[mf], 0, 0, 0);
            }
        }
    }

    size_t base = ((size_t)b * Tx + t0 + lr) * 64;
    u32x2 hv[4];
    f32x4 sko[4];
    #pragma unroll
    for (int mf = 0; mf < 4; ++mf) {
        hv[mf] = *(const u32x2*)(h_in + base + mf * 16 + lq * 4);
        if (!first) sko[mf] = *(const f32x4*)(skips + base + mf * 16 + lq * 4);
        else { sko[mf][0] = 0.f; sko[mf][1] = 0.f; sko[mf][2] = 0.f; sko[mf][3] = 0.f; }
    }

    unsigned char* myO = ldsO + wid * 2048;
    #pragma unroll
    for (int mf = 0; mf < 4; ++mf) {
        int p = lr;
        unsigned short ob[4];
        #pragma unroll
        for (int r = 0; r < 4; ++r) {
            float g = acc[mf][r];
            float f = acc[mf + 4][r];
            f = fminf(f, 15.f);
            g = fminf(g, 30.f);
            float ea = __builtin_amdgcn_exp2f(f * 2.8853900817779268f);
            float eb = __builtin_amdgcn_exp2f(g * 1.4426950408889634f);
            float num = (ea - 1.f) * eb;
            float den = (ea + 1.f) * (1.f + eb);
            ob[r] = f2bf(num * __builtin_amdgcn_rcpf(den));
        }
        u32x2 pk;
        pk[0] = (unsigned int)ob[0] | ((unsigned int)ob[1] << 16);
        pk[1] = (unsigned int)ob[2] | ((unsigned int)ob[3] << 16);
        *(u32x2*)(myO + p * 128 + ((mf * 32 + lq * 8) ^ ((p & 7) << 4))) = pk;
    }

    const float rt2 = 1.41421356237309505f;
    f32x4 racc[8];
    #pragma unroll
    for (int mf = 0; mf < 4; ++mf) {
        f32x4 rb = *(const f32x4*)(rsb + mf * 16 + lq * 4);
        unsigned short* hp = (unsigned short*)&hv[mf];
        f32x4 r;
        #pragma unroll
        for (int r_ = 0; r_ < 4; ++r_) r[r_] = fmaf(bf2f(hp[r_]), rt2, rb[r_]);
        racc[mf] = r;
    }
    #pragma unroll
    for (int mf = 0; mf < 4; ++mf)
        racc[mf + 4] = *(const f32x4*)(rsb + 64 + mf * 16 + lq * 4) + sko[mf];

    #pragma unroll
    for (int kc = 0; kc < 2; ++kc) {
        int p = lr;
        short8 ov = *(const short8*)(myO + p * 128 + ((kc * 64 + lq * 16) ^ ((p & 7) << 4)));
        #pragma unroll
        for (int mf = 0; mf < 8; ++mf) {
            int row = mf * 16 + lr;
            short8 af = *(const short8*)(ldsR + row * 128 + ((kc * 64 + lq * 16) ^ ((lr & 7) << 4)));
            racc[mf] = __builtin_amdgcn_mfma_f32_16x16x32_bf16(af, ov, racc[mf], 0, 0, 0);
        }
    }

    const float inv_s2 = 0.70710678118654752f;
    #pragma unroll
    for (int mf = 0; mf < 4; ++mf) {
        unsigned short hnew[4];
        #pragma unroll
        for (int r = 0; r < 4; ++r)
            hnew[r] = f2bf(racc[mf][r] * inv_s2);
        u32x2 hw;
        hw[0] = (unsigned int)hnew[0] | ((unsigned int)hnew[1] << 16);
        hw[1] = (unsigned int)hnew[2] | ((unsigned int)hnew[3] << 16);
        *(u32x2*)(h_out + base + mf * 16 + lq * 4) = hw;
        *(f32x4*)(skips + base + mf * 16 + lq * 4) = racc[mf + 4];
    }
}

// ---------------- HEX kernel: 6 fused layers (dils 1,2,4,8,16,32) ----------------
// Ext tile = 16 x 16 pos (128 core + 64 halo each side). h_{j+1} double-buffered
// in LDS (bf16, identical rounding). Validity ladder: h_j valid over +-(64 - sum
// dil_{<=j}); needed over +-(62 - ...) -- 2 positions spare at every level.
// Skip accumulated in registers across all 6 layers (one skips RMW total).
__launch_bounds__(512, 2)
__global__ void layer_hex_kernel(const unsigned short* __restrict__ h_in,
                                 unsigned short* __restrict__ h_out,
                                 float* __restrict__ skips,
                                 const unsigned short* __restrict__ wc2a,
                                 const unsigned short* __restrict__ wr2a,
                                 const float* __restrict__ gba,
                                 const float* __restrict__ rsba,
                                 int l0, int first) {
    __shared__ __align__(16) unsigned char lds[147456];
    unsigned char* ldsA = lds;             // 48K conv weights (restaged/pass)
    unsigned char* ldsR = lds + 49152;     // 16K rs weights
    unsigned char* ldsH0 = lds + 65536;    // 32K h buffer A (256 rows x 128B)
    unsigned char* ldsH1 = lds + 98304;    // 32K h buffer B
    unsigned char* ldsO = lds + 131072;    // 16K out exchange (2K/wave)

    int tid = threadIdx.x;
    int w = tid >> 6, lane = tid & 63, lr = lane & 15, lq = lane >> 4;
    const float rt2 = 1.41421356237309505f;
    const float inv_s2 = 0.70710678118654752f;

    int bid = blockIdx.x;
    int wg = (bid & 7) * 64 + (bid >> 3);   // batch k -> XCD k
    int b = wg >> 6;
    int t0 = (wg & 63) << 7;                // core start
    int ct = (w >= 4) ? w : w + 8;          // this wave's core tile (4..11)

    const unsigned short* hb = h_in + (size_t)b * Tx * 64;
    unsigned char* Hc = ldsH0;
    unsigned char* Hn = ldsH1;
    unsigned char* myO = ldsO + w * 2048;

    // skip accumulator (core tile), seeded with skips_old
    int gtc = t0 + (ct - 4) * 16 + lr;
    size_t cbase = ((size_t)b * Tx + gtc) * 64;
    f32x4 skacc[4];
    #pragma unroll
    for (int mf = 0; mf < 4; ++mf) {
        if (!first) skacc[mf] = *(const f32x4*)(skips + cbase + mf * 16 + lq * 4);
        else { skacc[mf][0] = 0.f; skacc[mf][1] = 0.f; skacc[mf][2] = 0.f; skacc[mf][3] = 0.f; }
    }

    u32x2 hnreg[2][4];   // h_{j} for owned tiles (k=0: tile w, k=1: tile w+8)

    #pragma unroll 1
    for (int j = 0; j < 6; ++j) {
        int l = l0 + j;
        int dil = 1 << j;
        int lo = (j <= 2) ? 0 : (j == 3 ? 1 : (j == 4 ? 2 : 4));
        int hi = 16 - lo;
        const float* gb = gba + (size_t)(l * 8 + b) * 128;
        const float* rsb = rsba + (size_t)l * 128;

        __syncthreads();   // prior pass's reads of ldsA/ldsR/Hc complete
        stageW(wc2a + (size_t)l * 24576, wr2a + (size_t)l * 8192, ldsA, ldsR, tid);
        __syncthreads();   // weights staged; Hc (prev Hn) visible to all

        #pragma unroll
        for (int k = 0; k < 2; ++k) {
            int tile = k ? w + 8 : w;
            if (tile >= lo && tile < hi) {
                int gt = t0 + (tile - 4) * 16 + lr;
                bool tv = ((unsigned)gt < (unsigned)Tx);

                // ---- conv ----
                f32x4 acc[8];
                #pragma unroll
                for (int mf = 0; mf < 8; ++mf)
                    acc[mf] = *(const f32x4*)(gb + mf * 16 + lq * 4);
                if (j == 0) {
                    #pragma unroll
                    for (int tap = 0; tap < 3; ++tap) {
                        int t = gt + (tap - 1);   // dil = 1
                        bool v = ((unsigned)t < (unsigned)Tx);
                        #pragma unroll
                        for (int kc = 0; kc < 2; ++kc) {
                            short8 z = {0, 0, 0, 0, 0, 0, 0, 0};
                            if (v) z = *(const short8*)(hb + t * 64 + kc * 32 + lq * 8);
                            #pragma unroll
                            for (int mf = 0; mf < 8; ++mf) {
                                int row = tap * 128 + mf * 16 + lr;
                                short8 af = *(const short8*)(ldsA + row * 128 + ((kc * 64 + lq * 16) ^ ((lr & 7) << 4)));
                                acc[mf] = __builtin_amdgcn_mfma_f32_16x16x32_bf16(af, z, acc[mf], 0, 0, 0);
                            }
                        }
                    }
                } else {
                    #pragma unroll
                    for (int tap = 0; tap < 3; ++tap) {
                        int row = tile * 16 + lr + (tap - 1) * dil;
                        row = max(0, min(255, row));   // clamp: only unused edge outputs affected
                        #pragma unroll
                        for (int kc = 0; kc < 2; ++kc) {
                            short8 z = *(const short8*)(Hc + row * 128 + ((kc * 64 + lq * 16) ^ ((row & 7) << 4)));
                            #pragma unroll
                            for (int mf = 0; mf < 8; ++mf) {
                                int wrow = tap * 128 + mf * 16 + lr;
                                short8 af = *(const short8*)(ldsA + wrow * 128 + ((kc * 64 + lq * 16) ^ ((lr & 7) << 4)));
                                acc[mf] = __builtin_amdgcn_mfma_f32_16x16x32_bf16(af, z, acc[mf], 0, 0, 0);
                            }
                        }
                    }
                }

                // ---- gating -> wave-private myO ----
                #pragma unroll
                for (int mf = 0; mf < 4; ++mf) {
                    int p = lr;
                    unsigned short ob[4];
                    #pragma unroll
                    for (int r = 0; r < 4; ++r) {
                        float g = acc[mf][r];
                        float f = acc[mf + 4][r];
                        f = fminf(f, 15.f);
                        g = fminf(g, 30.f);
                        float ea = __builtin_amdgcn_exp2f(f * 2.8853900817779268f);
                        float eb = __builtin_amdgcn_exp2f(g * 1.4426950408889634f);
                        float num = (ea - 1.f) * eb;
                        float den = (ea + 1.f) * (1.f + eb);
                        ob[r] = f2bf(num * __builtin_amdgcn_rcpf(den));
                    }
                    u32x2 pk;
                    pk[0] = (unsigned int)ob[0] | ((unsigned int)ob[1] << 16);
                    pk[1] = (unsigned int)ob[2] | ((unsigned int)ob[3] << 16);
                    *(u32x2*)(myO + p * 128 + ((mf * 32 + lq * 8) ^ ((p & 7) << 4))) = pk;
                }

                // ---- rs ----
                u32x2 hv[4];
                if (j == 0) {
                    #pragma unroll
                    for (int mf = 0; mf < 4; ++mf) {
                        u32x2 z; z[0] = 0u; z[1] = 0u;
                        if (tv) z = *(const u32x2*)(hb + gt * 64 + mf * 16 + lq * 4);
                        hv[mf] = z;
                    }
                } else {
                    #pragma unroll
                    for (int mf = 0; mf < 4; ++mf) hv[mf] = hnreg[k][mf];
                }
                f32x4 racc[8];
                #pragma unroll
                for (int mf = 0; mf < 4; ++mf) {
                    f32x4 rb = *(const f32x4*)(rsb + mf * 16 + lq * 4);
                    unsigned short* hp = (unsigned short*)&hv[mf];
                    f32x4 r;
                    #pragma unroll
                    for (int r_ = 0; r_ < 4; ++r_) r[r_] = fmaf(bf2f(hp[r_]), rt2, rb[r_]);
                    racc[mf] = r;
                }
                #pragma unroll
                for (int mf = 0; mf < 4; ++mf)
                    racc[mf + 4] = *(const f32x4*)(rsb + 64 + mf * 16 + lq * 4);
                #pragma unroll
                for (int kc = 0; kc < 2; ++kc) {
                    int p = lr;
                    short8 ov = *(const short8*)(myO + p * 128 + ((kc * 64 + lq * 16) ^ ((p & 7) << 4)));
                    #pragma unroll
                    for (int mf = 0; mf < 8; ++mf) {
                        int row = mf * 16 + lr;
                        short8 af = *(const short8*)(ldsR + row * 128 + ((kc * 64 + lq * 16) ^ ((lr & 7) << 4)));
                        racc[mf] = __builtin_amdgcn_mfma_f32_16x16x32_bf16(af, ov, racc[mf], 0, 0, 0);
                    }
                }

                // ---- h_{j+1} -> Hn (+ regs); skip accumulate; final writes ----
                int hrow = tile * 16 + lr;
                #pragma unroll
                for (int mf = 0; mf < 4; ++mf) {
                    u32x2 pk; pk[0] = 0u; pk[1] = 0u;
                    if (tv) {
                        unsigned short hn[4];
                        #pragma unroll
                        for (int r = 0; r < 4; ++r)
                            hn[r] = f2bf(racc[mf][r] * inv_s2);
                        pk[0] = (unsigned int)hn[0] | ((unsigned int)hn[1] << 16);
                        pk[1] = (unsigned int)hn[2] | ((unsigned int)hn[3] << 16);
                    }
                    *(u32x2*)(Hn + hrow * 128 + ((mf * 32 + lq * 8) ^ ((hrow & 7) << 4))) = pk;
                    hnreg[k][mf] = pk;
                }
                if (tile == ct) {
                    #pragma unroll
                    for (int mf = 0; mf < 4; ++mf)
                        skacc[mf] += racc[mf + 4];
                    if (j == 5) {
                        #pragma unroll
                        for (int mf = 0; mf < 4; ++mf) {
                            *(u32x2*)(h_out + cbase + mf * 16 + lq * 4) = hnreg[k][mf];
                            *(f32x4*)(skips + cbase + mf * 16 + lq * 4) = skacc[mf];
                        }
                    }
                }
            }
        }
        unsigned char* tmp = Hc; Hc = Hn; Hn = tmp;
    }
}

// ---------------- last layer (29) + fused skip_conv -> relu -> out_conv ----------------
__launch_bounds__(512, 2)
__global__ void layer_last_kernel(const unsigned short* __restrict__ h_in,
                                  const float* __restrict__ skips,
                                  const unsigned short* __restrict__ wc2,
                                  const unsigned short* __restrict__ wr2,
                                  const float* __restrict__ gbias,
                                  const float* __restrict__ rsb,
                                  const unsigned short* __restrict__ skw,
                                  const float* __restrict__ skb,
                                  const unsigned short* __restrict__ oww,
                                  const float* __restrict__ obias,
                                  float* __restrict__ y,
                                  int dil) {
    __shared__ __align__(16) unsigned char lds[81920];
    unsigned char* ldsA = lds;
    unsigned char* ldsR = lds + 49152;
    unsigned char* ldsO = lds + 65536;

    int tid = threadIdx.x;
    int wid = tid >> 6, lane = tid & 63, lr = lane & 15, lq = lane >> 4;

    stageW(wc2, wr2, ldsA, ldsR, tid);

    int bid = blockIdx.x;
    int wg = (bid & 7) * 64 + (bid >> 3);
    int b = wg >> 6;
    int t0 = ((wg & 63) << 7) + wid * 16;

    const unsigned short* hb = h_in + (size_t)b * Tx * 64;
    short8 bv[3][2];
    #pragma unroll
    for (int tap = 0; tap < 3; ++tap) {
        int toff = (tap - 1) * dil;
        int t = t0 + lr + toff;
        bool v = ((unsigned)t < (unsigned)Tx);
        #pragma unroll
        for (int kc = 0; kc < 2; ++kc) {
            short8 z = {0, 0, 0, 0, 0, 0, 0, 0};
            if (v) z = *(const short8*)(hb + t * 64 + kc * 32 + lq * 8);
            bv[tap][kc] = z;
        }
    }

    f32x4 acc[8];
    #pragma unroll
    for (int mf = 0; mf < 8; ++mf)
        acc[mf] = *(const f32x4*)(gbias + b * 128 + mf * 16 + lq * 4);
    __syncthreads();

    #pragma unroll
    for (int tap = 0; tap < 3; ++tap) {
        #pragma unroll
        for (int kc = 0; kc < 2; ++kc) {
            #pragma unroll
            for (int mf = 0; mf < 8; ++mf) {
                int row = tap * 128 + mf * 16 + lr;
                short8 af = *(const short8*)(ldsA + row * 128 + ((kc * 64 + lq * 16) ^ ((lr & 7) << 4)));
                acc[mf] = __builtin_amdgcn_mfma_f32_16x16x32_bf16(af, bv[tap][kc], acc[mf], 0, 0, 0);
            }
        }
    }

    size_t base = ((size_t)b * Tx + t0 + lr) * 64;
    f32x4 sko[4];
    #pragma unroll
    for (int mf = 0; mf < 4; ++mf)
        sko[mf] = *(const f32x4*)(skips + base + mf * 16 + lq * 4);

    unsigned char* myO = ldsO + wid * 2048;
    #pragma unroll
    for (int mf = 0; mf < 4; ++mf) {
        int p = lr;
        unsigned short ob[4];
        #pragma unroll
        for (int r = 0; r < 4; ++r) {
            float g = acc[mf][r];
            float f = acc[mf + 4][r];
            f = fminf(f, 15.f);
            g = fminf(g, 30.f);
            float ea = __builtin_amdgcn_exp2f(f * 2.8853900817779268f);
            float eb = __builtin_amdgcn_exp2f(g * 1.4426950408889634f);
            float num = (ea - 1.f) * eb;
            float den = (ea + 1.f) * (1.f + eb);
            ob[r] = f2bf(num * __builtin_amdgcn_rcpf(den));
        }
        u32x2 pk;
        pk[0] = (unsigned int)ob[0] | ((unsigned int)ob[1] << 16);
        pk[1] = (unsigned int)ob[2] | ((unsigned int)ob[3] << 16);
        *(u32x2*)(myO + p * 128 + ((mf * 32 + lq * 8) ^ ((p & 7) << 4))) = pk;
    }

    f32x4 racc[4];
    #pragma unroll
    for (int mf = 0; mf < 4; ++mf)
        racc[mf] = *(const f32x4*)(rsb + 64 + mf * 16 + lq * 4) + sko[mf];
    #pragma unroll
    for (int kc = 0; kc < 2; ++kc) {
        int p = lr;
        short8 ov = *(const short8*)(myO + p * 128 + ((kc * 64 + lq * 16) ^ ((p & 7) << 4)));
        #pragma unroll
        for (int mf = 0; mf < 4; ++mf) {
            int row = 64 + mf * 16 + lr;
            short8 af = *(const short8*)(ldsR + row * 128 + ((kc * 64 + lq * 16) ^ ((lr & 7) << 4)));
            racc[mf] = __builtin_amdgcn_mfma_f32_16x16x32_bf16(af, ov, racc[mf], 0, 0, 0);
        }
    }

    #pragma unroll
    for (int mf = 0; mf < 4; ++mf) {
        int p = lr;
        u32x2 pk;
        pk[0] = (unsigned int)f2bf(racc[mf][0]) | ((unsigned int)f2bf(racc[mf][1]) << 16);
        pk[1] = (unsigned int)f2bf(racc[mf][2]) | ((unsigned int)f2bf(racc[mf][3]) << 16);
        *(u32x2*)(myO + p * 128 + ((mf * 32 + lq * 8) ^ ((p & 7) << 4))) = pk;
    }

    f32x4 yacc[4];
    #pragma unroll
    for (int mf = 0; mf < 4; ++mf)
        yacc[mf] = *(const f32x4*)(skb + mf * 16 + lq * 4);
    #pragma unroll
    for (int kc = 0; kc < 2; ++kc) {
        int p = lr;
        short8 Bv = *(const short8*)(myO + p * 128 + ((kc * 64 + lq * 16) ^ ((p & 7) << 4)));
        #pragma unroll
        for (int mf = 0; mf < 4; ++mf) {
            short8 A1 = *(const short8*)(skw + (mf * 16 + lr) * 64 + kc * 32 + lq * 8);
            yacc[mf] = __builtin_amdgcn_mfma_f32_16x16x32_bf16(A1, Bv, yacc[mf], 0, 0, 0);
        }
    }
    #pragma unroll
    for (int mf = 0; mf < 4; ++mf) {
        int p = lr;
        u32x2 pk;
        pk[0] = (unsigned int)f2bf(fmaxf(yacc[mf][0], 0.f)) | ((unsigned int)f2bf(fmaxf(yacc[mf][1], 0.f)) << 16);
        pk[1] = (unsigned int)f2bf(fmaxf(yacc[mf][2], 0.f)) | ((unsigned int)f2bf(fmaxf(yacc[mf][3], 0.f)) << 16);
        *(u32x2*)(myO + p * 128 + ((mf * 32 + lq * 8) ^ ((p & 7) << 4))) = pk;
    }

    f32x4 oacc[5];
    #pragma unroll
    for (int mf = 0; mf < 5; ++mf)
        oacc[mf] = *(const f32x4*)(obias + mf * 16 + lq * 4);
    #pragma unroll
    for (int kc = 0; kc < 2; ++kc) {
        int p = lr;
        short8 B2 = *(const short8*)(myO + p * 128 + ((kc * 64 + lq * 16) ^ ((p & 7) << 4)));
        #pragma unroll
        for (int mf = 0; mf < 5; ++mf) {
            short8 A2 = *(const short8*)(oww + (mf * 16 + lr) * 64 + kc * 32 + lq * 8);
            oacc[mf] = __builtin_amdgcn_mfma_f32_16x16x32_bf16(A2, B2, oacc[mf], 0, 0, 0);
        }
    }
    int t = t0 + lr;
    #pragma unroll
    for (int mf = 0; mf < 5; ++mf) {
        #pragma unroll
        for (int r = 0; r < 4; ++r) {
            int m = mf * 16 + lq * 4 + r;
            y[((size_t)b * NM + m) * Tx + t] = oacc[mf][r];
        }
    }
}

extern "C" void kernel_launch(void* const* d_in, const int* in_sizes, int n_in,
                              void* d_out, int out_size, void* d_ws, size_t ws_size,
                              hipStream_t stream) {
    const float* x       = (const float*)d_in[0];
    const int*   tin     = (const int*)d_in[1];
    const float* c_emb   = (const float*)d_in[2];
    const float* in_w    = (const float*)d_in[3];
    const float* in_b    = (const float*)d_in[4];
    const float* te_w1   = (const float*)d_in[5];
    const float* te_b1   = (const float*)d_in[6];
    const float* te_w2   = (const float*)d_in[7];
    const float* te_b2   = (const float*)d_in[8];
    const float* dconv_w = (const float*)d_in[9];
    const float* dconv_b = (const float*)d_in[10];
    const float* tproj_w = (const float*)d_in[11];
    const float* tproj_b = (const float*)d_in[12];
    const float* cproj_w = (const float*)d_in[13];
    const float* cproj_b = (const float*)d_in[14];
    const float* rs_w    = (const float*)d_in[15];
    const float* rs_b    = (const float*)d_in[16];
    const float* skip_w  = (const float*)d_in[17];
    const float* skip_b  = (const float*)d_in[18];
    const float* out_w   = (const float*)d_in[19];
    const float* out_b   = (const float*)d_in[20];

    char* ws = (char*)d_ws;
    float* gbias          = (float*)(ws + 4096);
    unsigned short* skw16 = (unsigned short*)(ws + 126976);
    unsigned short* oww16 = (unsigned short*)(ws + 135168);
    unsigned short* wc2   = (unsigned short*)(ws + 145408);
    unsigned short* wr2   = (unsigned short*)(ws + 1619968);
    unsigned short* h0    = (unsigned short*)(ws + 2111488);
    unsigned short* h1    = (unsigned short*)(ws + 10500096);
    float* skips          = (float*)(ws + 18888704);

    setup_kernel<<<317, 512, 0, stream>>>(dconv_w, rs_w, skip_w, out_w,
                                          wc2, wr2, skw16, oww16,
                                          x, in_w, in_b, h0);
    gbias_kernel<<<240, 512, 0, stream>>>(tin, te_w1, te_b1, te_w2, te_b2,
                                          c_emb, tproj_w, tproj_b,
                                          cproj_w, cproj_b, dconv_b, gbias);

    unsigned short* hin = h0;
    unsigned short* hout = h1;
    int i = 0;
    while (i < NL - 1) {
        int dec = i % 10;
        if (dec == 0 && i + 5 < NL - 1) {
            // hex: layers i .. i+5 (dils 1,2,4,8,16,32)
            layer_hex_kernel<<<512, 512, 0, stream>>>(hin, hout, skips,
                                                      wc2, wr2, gbias, rs_b,
                                                      i, i == 0 ? 1 : 0);
            unsigned short* tmp = hin; hin = hout; hout = tmp;
            i += 6;
        } else {
            int dil = 1 << dec;
            layer_kernel<<<512, 512, 0, stream>>>(hin, hout, skips,
                                                  wc2 + (size_t)i * 24576,
                                                  wr2 + (size_t)i * 8192,
                                                  gbias + (size_t)i * 1024,
                                                  rs_b + (size_t)i * 128,
                                                  dil, 0);
            unsigned short* tmp = hin; hin = hout; hout = tmp;
            i += 1;
        }
    }
    layer_last_kernel<<<512, 512, 0, stream>>>(hin, skips,
                                               wc2 + (size_t)(NL - 1) * 24576,
                                               wr2 + (size_t)(NL - 1) * 8192,
                                               gbias + (size_t)(NL - 1) * 1024,
                                               rs_b + (size_t)(NL - 1) * 128,
                                               skw16, skip_b, oww16, out_b,
                                               (float*)d_out, 1 << ((NL - 1) % 10));
}